// Round 19
// baseline (558.828 us; speedup 1.0000x reference)
//
#include <hip/hip_runtime.h>

#define L_ 2
#define H_ 2048
#define NH_ 16
#define NKV_ 2
#define HD_ 128
#define S_ 1024
#define P_ 1024
#define T_ 2048
#define FF_ 5632
#define QKVN_ 2560   // NH*HD + 2*NKV*HD
#define KOFF_ 2048
#define VOFF_ 2304

#define EPS_ 1e-6f
#define SCALE_ 0.08838834764831845f   // 1/sqrt(128)
#define DEFER_THR_ 8.0f

typedef __bf16 bf16_t;
typedef unsigned int u32;
typedef __bf16 bx8 __attribute__((ext_vector_type(8)));
typedef __bf16 bx4 __attribute__((ext_vector_type(4)));
typedef float  fx4 __attribute__((ext_vector_type(4)));

__device__ __forceinline__ fx4 mfma16(bx8 a, bx8 b, fx4 c) {
  return __builtin_amdgcn_mfma_f32_16x16x32_bf16(a, b, c, 0, 0, 0);
}

// global->LDS direct, 16B per lane; lds dest = wave-uniform base + lane*16
#define GLL16(gsrc, ldst) __builtin_amdgcn_global_load_lds( \
    (__attribute__((address_space(1))) void*)(gsrc),        \
    (__attribute__((address_space(3))) void*)(ldst), 16, 0, 0)

// opaque LDS ops: compiler cannot attach vmem (global_load_lds) dependencies,
// so it cannot insert a hidden vmcnt(0) before them. Caller must lgkmcnt-fence.
__device__ __forceinline__ bx8 lds_read_b128(char* p) {
  u32 a = (u32)(uintptr_t)(__attribute__((address_space(3))) void*)p;
  bx8 d;
  asm volatile("ds_read_b128 %0, %1" : "=v"(d) : "v"(a));
  return d;
}
__device__ __forceinline__ void lds_write_b16(char* p, float v) {
  u32 a = (u32)(uintptr_t)(__attribute__((address_space(3))) void*)p;
  bf16_t b = (bf16_t)v;
  u32 d = (u32)__builtin_bit_cast(unsigned short, b);
  asm volatile("ds_write_b16 %0, %1" :: "v"(a), "v"(d));
}

#define LGKM(n) asm volatile("s_waitcnt lgkmcnt(" #n ")" ::: "memory"); __builtin_amdgcn_sched_barrier(0)

// bijective XCD swizzle (m204): consecutive work-ids land on the same XCD
__device__ __forceinline__ int xcd_swizzle(int orig, int nwg) {
  int q = nwg >> 3, r = nwg & 7;
  int xcd = orig & 7, lid = orig >> 3;
  return (xcd < r ? xcd * (q + 1) : r * (q + 1) + (xcd - r) * q) + lid;
}

// ---------------- RoPE tables ----------------
__global__ void k_rope_tables(const int* __restrict__ pos, float* __restrict__ ct, float* __restrict__ st) {
  int i = blockIdx.x * 256 + threadIdx.x;
  if (i >= S_ * 64) return;
  int s = i >> 6, d = i & 63;
  float p = (float)pos[s];
  float inv = expf(-(float)(2 * d) * (13.815510557964274f / 128.0f));  // theta=1e6
  float f = p * inv;
  ct[i] = cosf(f);
  st[i] = sinf(f);
}

__global__ void k_copy4(const float* __restrict__ in, float* __restrict__ out, int n4) {
  int i = blockIdx.x * 256 + threadIdx.x;
  if (i < n4) ((fx4*)out)[i] = ((const fx4*)in)[i];
}

// concat bias: [L][2560] = bq | bk | bv
__global__ void k_cbias(const float* __restrict__ bq, const float* __restrict__ bk,
                        const float* __restrict__ bv, float* __restrict__ cb) {
  int i = blockIdx.x * 256 + threadIdx.x;
  if (i >= L_ * QKVN_) return;
  int l = i / QKVN_, j = i % QKVN_;
  float v;
  if (j < KOFF_)      v = bq[l * KOFF_ + j];
  else if (j < VOFF_) v = bk[l * (NKV_ * HD_) + j - KOFF_];
  else                v = bv[l * (NKV_ * HD_) + j - VOFF_];
  cb[i] = v;
}

// ---------------- RMSNorm (one block per row) ----------------
template<int OUTBF>
__global__ __launch_bounds__(256) void k_rmsnorm(const float* __restrict__ x, const float* __restrict__ w,
                                                 void* __restrict__ y) {
  int row = blockIdx.x, tid = threadIdx.x;
  const fx4* xr = (const fx4*)(x + (size_t)row * H_);
  fx4 v0 = xr[tid], v1 = xr[tid + 256];
  float ss = v0[0]*v0[0] + v0[1]*v0[1] + v0[2]*v0[2] + v0[3]*v0[3]
           + v1[0]*v1[0] + v1[1]*v1[1] + v1[2]*v1[2] + v1[3]*v1[3];
  #pragma unroll
  for (int off = 32; off > 0; off >>= 1) ss += __shfl_xor(ss, off);
  __shared__ float red[4];
  if ((tid & 63) == 0) red[tid >> 6] = ss;
  __syncthreads();
  float tot = red[0] + red[1] + red[2] + red[3];
  float rs = rsqrtf(tot * (1.0f / H_) + EPS_);
  const fx4* wr_ = (const fx4*)w;
  fx4 w0 = wr_[tid], w1 = wr_[tid + 256];
  if (OUTBF) {
    bf16_t* yb = (bf16_t*)y + (size_t)row * H_;
    bx4 o0, o1;
    #pragma unroll
    for (int i = 0; i < 4; i++) { o0[i] = (bf16_t)(v0[i] * rs * w0[i]); o1[i] = (bf16_t)(v1[i] * rs * w1[i]); }
    *(bx4*)&yb[tid * 4] = o0;
    *(bx4*)&yb[(tid + 256) * 4] = o1;
  } else {
    float* yf = (float*)y + (size_t)row * H_;
    fx4 o0, o1;
    #pragma unroll
    for (int i = 0; i < 4; i++) { o0[i] = v0[i] * rs * w0[i]; o1[i] = v1[i] * rs * w1[i]; }
    *(fx4*)&yf[tid * 4] = o0;
    *(fx4*)&yf[(tid + 256) * 4] = o1;
  }
}

// ---------------- weight transpose+convert: out[C][R] = bf16(in[R][C]^T) ----------------
__global__ __launch_bounds__(256) void k_transpose_w(const float* __restrict__ in, bf16_t* __restrict__ out,
                                                     int R, int C) {
  __shared__ __attribute__((aligned(16))) float Tt[64 * 68];
  int tid = threadIdx.x;
  int c0 = blockIdx.x * 64, r0 = blockIdx.y * 64;
  #pragma unroll
  for (int j = 0; j < 4; j++) {
    int c = j * 256 + tid;
    int row = c >> 4, col = (c & 15) * 4;
    *(fx4*)&Tt[row * 68 + col] = *(const fx4*)&in[(size_t)(r0 + row) * C + c0 + col];
  }
  __syncthreads();
  #pragma unroll
  for (int j = 0; j < 2; j++) {
    int c = j * 256 + tid;
    int n = c >> 3, ko = (c & 7) * 8;
    bx8 o;
    #pragma unroll
    for (int i = 0; i < 8; i++) o[i] = (bf16_t)Tt[(ko + i) * 68 + n];
    *(bx8*)&out[(size_t)(c0 + n) * R + r0 + ko] = o;
  }
}

// ---------------- GEMM 64x128: C[M,N] = A[M,K](bf16) * Bt[N,K]^T ----------------
// 2-buffer depth-1 pipeline (48KB LDS), counted vmcnt(6), raw s_barrier,
// opaque asm ds_read_b128, split-lgkm(6/0) + setprio.
// SPLIT>1: each split does kLen of K and atomicAdds f32 partials into out.
template<int OUTBF, int HASB, int HASR, int HASG, int SPLIT>
__global__ __launch_bounds__(256) void k_gemm(const bf16_t* __restrict__ A, const bf16_t* __restrict__ Bt,
                                              const float* __restrict__ bias, const float* __restrict__ res,
                                              const bf16_t* __restrict__ gmul,
                                              void* __restrict__ out, int M, int N, int lda, int kLen, int gy) {
  __shared__ __attribute__((aligned(16))) bf16_t sA[2][64 * 64];
  __shared__ __attribute__((aligned(16))) bf16_t sB[2][128 * 64];
  int tid = threadIdx.x;
  int w = tid >> 6, lane = tid & 63, g = lane >> 4, r = lane & 15;
  int wr = w >> 1, wc = w & 1;
  int swzid = xcd_swizzle((int)blockIdx.x, (int)gridDim.x);
  int per = (int)gridDim.x / SPLIT;
  int sp = swzid / per;
  int rem = swzid - sp * per;
  int m0 = (rem % gy) * 64;
  int n0 = (rem / gy) * 128;
  A  += (size_t)sp * kLen;
  Bt += (size_t)sp * kLen;
  fx4 acc[2][4] = {};
  int swz = (r & 7) << 4;
  int col0 = (g * 16) ^ swz;
  int col1 = (64 + g * 16) ^ swz;
  int wbase = (tid & ~63) * 16;
  int nk = kLen >> 6;

  auto STAGE = [&](int buf, int k0) {
    #pragma unroll
    for (int j = 0; j < 2; j++) {
      int d = (j * 256 + tid) * 16;
      int row = d >> 7;
      int inrow = (d & 127) ^ ((row & 7) << 4);
      GLL16((const char*)(A + (size_t)(m0 + row) * lda + k0) + inrow,
            (char*)&sA[buf][0] + j * 4096 + wbase);
    }
    #pragma unroll
    for (int j = 0; j < 4; j++) {
      int d = (j * 256 + tid) * 16;
      int row = d >> 7;
      int inrow = (d & 127) ^ ((row & 7) << 4);
      GLL16((const char*)(Bt + (size_t)(n0 + row) * lda + k0) + inrow,
            (char*)&sB[buf][0] + j * 4096 + wbase);
    }
  };

  STAGE(0, 0);                                     // 6 outstanding
  int cur = 0;
  for (int t = 0; t < nk; t++) {
    if (t + 1 < nk) {
      STAGE(cur ^ 1, (t + 1) << 6);                // 12 outstanding
      asm volatile("s_waitcnt vmcnt(6)" ::: "memory");  // cur's loads landed
    } else {
      asm volatile("s_waitcnt vmcnt(0)" ::: "memory");
    }
    __builtin_amdgcn_s_barrier();                  // all waves' cur-stage visible
    __builtin_amdgcn_sched_barrier(0);
    char* pa = (char*)&sA[cur][0] + (wr * 32 + r) * 128;
    char* pb = (char*)&sB[cur][0] + (wc * 64 + r) * 128;
    bx8 fa[2][2], fb[4][2];
    fa[0][0] = lds_read_b128(pa + col0);
    fa[1][0] = lds_read_b128(pa + 2048 + col0);
    #pragma unroll
    for (int n = 0; n < 4; n++) fb[n][0] = lds_read_b128(pb + n * 2048 + col0);
    fa[0][1] = lds_read_b128(pa + col1);
    fa[1][1] = lds_read_b128(pa + 2048 + col1);
    #pragma unroll
    for (int n = 0; n < 4; n++) fb[n][1] = lds_read_b128(pb + n * 2048 + col1);
    LGKM(6);                                       // col0 set complete
    __builtin_amdgcn_s_setprio(1);
    #pragma unroll
    for (int n = 0; n < 4; n++) {
      acc[0][n] = mfma16(fa[0][0], fb[n][0], acc[0][n]);
      acc[1][n] = mfma16(fa[1][0], fb[n][0], acc[1][n]);
    }
    __builtin_amdgcn_s_setprio(0);
    LGKM(0);                                       // col1 set complete
    __builtin_amdgcn_s_setprio(1);
    #pragma unroll
    for (int n = 0; n < 4; n++) {
      acc[0][n] = mfma16(fa[0][1], fb[n][1], acc[0][n]);
      acc[1][n] = mfma16(fa[1][1], fb[n][1], acc[1][n]);
    }
    __builtin_amdgcn_s_setprio(0);
    if (t + 1 < nk) {
      __builtin_amdgcn_s_barrier();                // reads done before buf reuse
      __builtin_amdgcn_sched_barrier(0);
    }
    cur ^= 1;
  }
  #pragma unroll
  for (int m = 0; m < 2; m++)
    #pragma unroll
    for (int n = 0; n < 4; n++) {
      int col = n0 + wc * 64 + n * 16 + r;
      #pragma unroll
      for (int rr = 0; rr < 4; rr++) {
        int row = m0 + wr * 32 + m * 16 + 4 * g + rr;
        float v = acc[m][n][rr];
        if (SPLIT > 1) {
          atomicAdd(&((float*)out)[(size_t)row * N + col], v);
        } else {
          if (HASB) v += bias[col];
          if (HASR) v += res[(size_t)row * N + col];
          if (HASG) {
            float x = (float)gmul[(size_t)row * N + col];
            v = (x / (1.0f + __expf(-x))) * v;
          }
          if (OUTBF) ((bf16_t*)out)[(size_t)row * N + col] = (bf16_t)v;
          else       ((float*)out)[(size_t)row * N + col] = v;
        }
      }
    }
}

// ---------------- GEMM 128x128: higher arithmetic intensity (64 FLOP/staged-byte) ----------------
// 4 waves a 64x64, acc[4][4]; 2-buffer depth-1 pipeline (64KB LDS -> 2 blocks/CU),
// counted vmcnt(8), split-lgkm(8/0) + setprio.
template<int OUTBF, int HASG, int SPLIT>
__global__ __launch_bounds__(256) void k_gemm_big(const bf16_t* __restrict__ A, const bf16_t* __restrict__ Bt,
                                                  const bf16_t* __restrict__ gmul,
                                                  void* __restrict__ out, int M, int N, int lda, int kLen, int gy) {
  __shared__ __attribute__((aligned(16))) bf16_t sA[2][128 * 64];
  __shared__ __attribute__((aligned(16))) bf16_t sB[2][128 * 64];
  int tid = threadIdx.x;
  int w = tid >> 6, lane = tid & 63, g = lane >> 4, r = lane & 15;
  int wr = w >> 1, wc = w & 1;
  int swzid = xcd_swizzle((int)blockIdx.x, (int)gridDim.x);
  int per = (int)gridDim.x / SPLIT;
  int sp = swzid / per;
  int rem = swzid - sp * per;
  int m0 = (rem % gy) * 128;
  int n0 = (rem / gy) * 128;
  A  += (size_t)sp * kLen;
  Bt += (size_t)sp * kLen;
  fx4 acc[4][4] = {};
  int swz = (r & 7) << 4;
  int col0 = (g * 16) ^ swz;
  int col1 = (64 + g * 16) ^ swz;
  int wbase = (tid & ~63) * 16;
  int nk = kLen >> 6;

  auto STAGE = [&](int buf, int k0) {
    #pragma unroll
    for (int j = 0; j < 4; j++) {
      int d = (j * 256 + tid) * 16;
      int row = d >> 7;
      int inrow = (d & 127) ^ ((row & 7) << 4);
      GLL16((const char*)(A + (size_t)(m0 + row) * lda + k0) + inrow,
            (char*)&sA[buf][0] + j * 4096 + wbase);
    }
    #pragma unroll
    for (int j = 0; j < 4; j++) {
      int d = (j * 256 + tid) * 16;
      int row = d >> 7;
      int inrow = (d & 127) ^ ((row & 7) << 4);
      GLL16((const char*)(Bt + (size_t)(n0 + row) * lda + k0) + inrow,
            (char*)&sB[buf][0] + j * 4096 + wbase);
    }
  };

  STAGE(0, 0);                                     // 8 outstanding
  int cur = 0;
  for (int t = 0; t < nk; t++) {
    if (t + 1 < nk) {
      STAGE(cur ^ 1, (t + 1) << 6);                // 16 outstanding
      asm volatile("s_waitcnt vmcnt(8)" ::: "memory");  // cur's 8 landed
    } else {
      asm volatile("s_waitcnt vmcnt(0)" ::: "memory");
    }
    __builtin_amdgcn_s_barrier();
    __builtin_amdgcn_sched_barrier(0);
    char* pa = (char*)&sA[cur][0] + (wr * 64 + r) * 128;
    char* pb = (char*)&sB[cur][0] + (wc * 64 + r) * 128;
    bx8 fa[4][2], fb[4][2];
    #pragma unroll
    for (int m = 0; m < 4; m++) fa[m][0] = lds_read_b128(pa + m * 2048 + col0);
    #pragma unroll
    for (int n = 0; n < 4; n++) fb[n][0] = lds_read_b128(pb + n * 2048 + col0);
    #pragma unroll
    for (int m = 0; m < 4; m++) fa[m][1] = lds_read_b128(pa + m * 2048 + col1);
    #pragma unroll
    for (int n = 0; n < 4; n++) fb[n][1] = lds_read_b128(pb + n * 2048 + col1);
    LGKM(8);                                       // col0 set (8 reads) complete
    __builtin_amdgcn_s_setprio(1);
    #pragma unroll
    for (int m = 0; m < 4; m++)
      #pragma unroll
      for (int n = 0; n < 4; n++)
        acc[m][n] = mfma16(fa[m][0], fb[n][0], acc[m][n]);
    __builtin_amdgcn_s_setprio(0);
    LGKM(0);                                       // col1 set complete
    __builtin_amdgcn_s_setprio(1);
    #pragma unroll
    for (int m = 0; m < 4; m++)
      #pragma unroll
      for (int n = 0; n < 4; n++)
        acc[m][n] = mfma16(fa[m][1], fb[n][1], acc[m][n]);
    __builtin_amdgcn_s_setprio(0);
    if (t + 1 < nk) {
      __builtin_amdgcn_s_barrier();
      __builtin_amdgcn_sched_barrier(0);
    }
    cur ^= 1;
  }
  #pragma unroll
  for (int m = 0; m < 4; m++)
    #pragma unroll
    for (int n = 0; n < 4; n++) {
      int col = n0 + wc * 64 + n * 16 + r;
      #pragma unroll
      for (int rr = 0; rr < 4; rr++) {
        int row = m0 + wr * 64 + m * 16 + 4 * g + rr;
        float v = acc[m][n][rr];
        if (SPLIT > 1) {
          atomicAdd(&((float*)out)[(size_t)row * N + col], v);
        } else {
          if (HASG) {
            float x = (float)gmul[(size_t)row * N + col];
            v = (x / (1.0f + __expf(-x))) * v;
          }
          if (OUTBF) ((bf16_t*)out)[(size_t)row * N + col] = (bf16_t)v;
          else       ((float*)out)[(size_t)row * N + col] = v;
        }
      }
    }
}

// ---------------- RoPE on Q: qkv[S][2560] bf16 -> [NH][S][HD] bf16 ----------------
__global__ void k_rope_q(const bf16_t* __restrict__ qkv, const float* __restrict__ ct,
                         const float* __restrict__ st, bf16_t* __restrict__ qout) {
  int i = blockIdx.x * 256 + threadIdx.x;
  if (i >= S_ * NH_ * 64) return;
  int d = i & 63, h = (i >> 6) & 15, s = i >> 10;
  size_t ib = (size_t)s * QKVN_ + h * HD_;
  float x1 = (float)qkv[ib + d];
  float x2 = (float)qkv[ib + d + 64];
  float c = ct[s * 64 + d], sn = st[s * 64 + d];
  size_t ob = ((size_t)h * S_ + s) * HD_;
  qout[ob + d]      = (bf16_t)(x1 * c - x2 * sn);
  qout[ob + d + 64] = (bf16_t)(x2 * c + x1 * sn);
}

// ---------------- K: rope new keys + concat past -> bf16 [NKV][T][HD] + f32 present ----------------
__global__ void k_build_k(const bf16_t* __restrict__ qkv, const float* __restrict__ pastk,
                          const float* __restrict__ ct, const float* __restrict__ st,
                          bf16_t* __restrict__ kc, float* __restrict__ pk_out) {
  int i = blockIdx.x * 256 + threadIdx.x;
  if (i >= NKV_ * T_ * 64) return;
  int d = i & 63, t = (i >> 6) & (T_ - 1), kv = i >> 17;
  size_t cb = ((size_t)kv * T_ + t) * HD_;
  if (t < P_) {
    size_t pb = ((size_t)kv * P_ + t) * HD_;
    float a = pastk[pb + d], b = pastk[pb + d + 64];
    kc[cb + d] = (bf16_t)a; kc[cb + d + 64] = (bf16_t)b;
    pk_out[cb + d] = a;     pk_out[cb + d + 64] = b;
  } else {
    int s = t - P_;
    size_t ib = (size_t)s * QKVN_ + KOFF_ + kv * HD_;
    float x1 = (float)qkv[ib + d];
    float x2 = (float)qkv[ib + d + 64];
    float c = ct[s * 64 + d], sn = st[s * 64 + d];
    float k1 = x1 * c - x2 * sn, k2 = x2 * c + x1 * sn;
    kc[cb + d] = (bf16_t)k1; kc[cb + d + 64] = (bf16_t)k2;
    pk_out[cb + d] = k1;     pk_out[cb + d + 64] = k2;
  }
}

// ---------------- V: concat past+new -> VT bf16 [NKV][HD][T] + f32 present ----------------
__global__ __launch_bounds__(256) void k_build_vt(const bf16_t* __restrict__ qkv, const float* __restrict__ pastv,
                                                  bf16_t* __restrict__ vt, float* __restrict__ pv_out) {
  int t0 = blockIdx.x * 64, d0 = blockIdx.y * 64, kv = blockIdx.z;
  __shared__ __attribute__((aligned(16))) float Tt[64 * 68];
  int tid = threadIdx.x;
  if (t0 < P_) {
    #pragma unroll
    for (int j = 0; j < 4; j++) {
      int c = j * 256 + tid;
      int row = c >> 4, col = (c & 15) * 4;
      int t = t0 + row;
      fx4 v = *(const fx4*)&pastv[((size_t)kv * P_ + t) * HD_ + d0 + col];
      *(fx4*)&Tt[row * 68 + col] = v;
      *(fx4*)&pv_out[((size_t)kv * T_ + t) * HD_ + d0 + col] = v;
    }
  } else {
    #pragma unroll
    for (int j = 0; j < 4; j++) {
      int c = j * 256 + tid;
      int row = c >> 4, col = (c & 15) * 4;
      int t = t0 + row;
      bx4 b = *(const bx4*)&qkv[(size_t)(t - P_) * QKVN_ + VOFF_ + kv * HD_ + d0 + col];
      fx4 v;
      #pragma unroll
      for (int q = 0; q < 4; q++) v[q] = (float)b[q];
      *(fx4*)&Tt[row * 68 + col] = v;
      *(fx4*)&pv_out[((size_t)kv * T_ + t) * HD_ + d0 + col] = v;
    }
  }
  __syncthreads();
  #pragma unroll
  for (int j = 0; j < 2; j++) {
    int c = j * 256 + tid;
    int n = c >> 3, ko = (c & 7) * 8;
    bx8 o;
    #pragma unroll
    for (int i = 0; i < 8; i++) o[i] = (bf16_t)Tt[(ko + i) * 68 + n];
    *(bx8*)&vt[((size_t)kv * HD_ + d0 + n) * T_ + t0 + ko] = o;
  }
}

// ---------------- flash attention (stable): balanced chunk mapping, V-reads pre-softmax ----------------
__global__ __launch_bounds__(128) void k_attn(const bf16_t* __restrict__ Q, const bf16_t* __restrict__ Kc,
                                              const bf16_t* __restrict__ VT, bf16_t* __restrict__ O) {
  __shared__ __attribute__((aligned(16))) bf16_t Klds[2][64 * 128];
  __shared__ __attribute__((aligned(16))) bf16_t Vlds[2][128 * 64];
  __shared__ __attribute__((aligned(16))) bf16_t Plds[2][16][72];
  int tid = threadIdx.x;               // 0..127
  int w = tid >> 6, lane = tid & 63, g = lane >> 4, r = lane & 15;
  int b = blockIdx.x;                  // 0..511
  int half = b >> 8;                   // = kv
  int idx = b & 255;
  int cx = idx & 31;
  int chunk = half ? (31 - cx) : cx;   // complementary chunks land on same CU
  int h = (half << 3) | (idx >> 5);    // heads 0-7 (kv0) / 8-15 (kv1)
  int kv = half;
  int m0 = chunk * 32;
  int qr0 = m0 + w * 16;
  const bf16_t* qb = Q + ((size_t)h * S_ + qr0 + r) * HD_ + g * 8;
  bx8 qf[4];
  #pragma unroll
  for (int kc = 0; kc < 4; kc++) qf[kc] = *(const bx8*)(qb + kc * 32);
  fx4 of[8] = {};
  float mrun[4], lrun[4];
  #pragma unroll
  for (int i = 0; i < 4; i++) { mrun[i] = -1e30f; lrun[i] = 0.0f; }
  int lim = P_ + qr0 + 4 * g;
  int ntile = (P_ + m0 + 32 + 63) >> 6;
  const char* kg = (const char*)(Kc + (size_t)kv * T_ * HD_);
  const char* vg = (const char*)(VT + (size_t)kv * HD_ * T_);
  int wbase = (tid & ~63) * 16;        // w*1024

  auto STAGE = [&](int buf, int t0) {
    #pragma unroll
    for (int j = 0; j < 8; j++) {      // K: 64 rows x 256B = 16KB, 2KB/round
      int D = j * 2048 + tid * 16;
      int row = D >> 8, inrow = D & 255;
      const char* src = kg + (size_t)(t0 + row) * 256 + (inrow ^ ((row & 7) << 4));
      GLL16(src, (char*)&Klds[buf][0] + j * 2048 + wbase);
    }
    #pragma unroll
    for (int j = 0; j < 8; j++) {      // V^T: 128 rows x 128B = 16KB
      int D = j * 2048 + tid * 16;
      int row = D >> 7, inrow = D & 127;
      const char* src = vg + (size_t)row * 4096 + (size_t)t0 * 2 + (inrow ^ ((row & 7) << 4));
      GLL16(src, (char*)&Vlds[buf][0] + j * 2048 + wbase);
    }
  };

  STAGE(0, 0);
  asm volatile("s_waitcnt vmcnt(0)" ::: "memory");
  __builtin_amdgcn_s_barrier();
  __builtin_amdgcn_sched_barrier(0);
  int cur = 0;
  for (int t = 0; t < ntile; t++) {
    int t0 = t * 64;
    if (t + 1 < ntile) {
      STAGE(cur ^ 1, t0 + 64);                             // issue next tile (16 vm ops)
      asm volatile("s_waitcnt vmcnt(16)" ::: "memory");    // cur's stage landed
    } else {
      asm volatile("s_waitcnt vmcnt(0)" ::: "memory");
    }
    __builtin_amdgcn_s_barrier();                          // all waves' cur-stage visible
    __builtin_amdgcn_sched_barrier(0);
    // ---- QK^T: 16 opaque ds_reads, counted lgkm, interleaved MFMAs ----
    char* kb = (char*)&Klds[cur][0];
    char* vb = (char*)&Vlds[cur][0];
    bx8 kf[4][4];
    #pragma unroll
    for (int nt = 0; nt < 4; nt++) {
      int row = nt * 16 + r;
      char* kr = kb + row * 256;
      int sz = (row & 7) << 4;
      #pragma unroll
      for (int kc = 0; kc < 4; kc++)
        kf[nt][kc] = lds_read_b128(kr + (((kc * 32 + g * 8) * 2) ^ sz));
    }
    fx4 sc[4] = {};
    LGKM(12);
    #pragma unroll
    for (int kc = 0; kc < 4; kc++) sc[0] = mfma16(qf[kc], kf[0][kc], sc[0]);
    LGKM(8);
    #pragma unroll
    for (int kc = 0; kc < 4; kc++) sc[1] = mfma16(qf[kc], kf[1][kc], sc[1]);
    LGKM(4);
    #pragma unroll
    for (int kc = 0; kc < 4; kc++) sc[2] = mfma16(qf[kc], kf[2][kc], sc[2]);
    LGKM(0);
    #pragma unroll
    for (int kc = 0; kc < 4; kc++) sc[3] = mfma16(qf[kc], kf[3][kc], sc[3]);
    // ---- issue all 16 V reads NOW; latency hides under softmax VALU ----
    bx8 vf0[8], vf1[8];
    #pragma unroll
    for (int dt = 0; dt < 8; dt++) {
      int row = dt * 16 + r;
      vf0[dt] = lds_read_b128(vb + row * 128 + (((g * 8) * 2) ^ ((row & 7) << 4)));
    }
    #pragma unroll
    for (int dt = 0; dt < 8; dt++) {
      int row = dt * 16 + r;
      vf1[dt] = lds_read_b128(vb + row * 128 + (((32 + g * 8) * 2) ^ ((row & 7) << 4)));
    }
    // ---- softmax (defer-max); V reads complete during this phase ----
    float lm[4] = {-1e30f, -1e30f, -1e30f, -1e30f};
    #pragma unroll
    for (int nt = 0; nt < 4; nt++)
      #pragma unroll
      for (int rr = 0; rr < 4; rr++) {
        int key = t0 + nt * 16 + r;
        float sv = sc[nt][rr] * SCALE_;
        sv = (key > lim + rr) ? -1e30f : sv;
        sc[nt][rr] = sv;
        lm[rr] = fmaxf(lm[rr], sv);
      }
    int ok = (lm[0] <= mrun[0] + DEFER_THR_) & (lm[1] <= mrun[1] + DEFER_THR_) &
             (lm[2] <= mrun[2] + DEFER_THR_) & (lm[3] <= mrun[3] + DEFER_THR_);
    if (!__all(ok)) {
      float av[4];
      #pragma unroll
      for (int off = 1; off < 16; off <<= 1)
        #pragma unroll
        for (int rr = 0; rr < 4; rr++) lm[rr] = fmaxf(lm[rr], __shfl_xor(lm[rr], off));
      #pragma unroll
      for (int rr = 0; rr < 4; rr++) {
        float mn = fmaxf(mrun[rr], lm[rr]);
        av[rr] = __expf(mrun[rr] - mn);
        mrun[rr] = mn;
        lrun[rr] *= av[rr];
      }
      #pragma unroll
      for (int f = 0; f < 8; f++)
        #pragma unroll
        for (int rr = 0; rr < 4; rr++) of[f][rr] *= av[rr];
    }
    // P writes: cols 0-31 (nt 0,1) then pa0 read; cols 32-63 (nt 2,3) then pa1
    #pragma unroll
    for (int nt = 0; nt < 2; nt++)
      #pragma unroll
      for (int rr = 0; rr < 4; rr++) {
        float pr = __expf(sc[nt][rr] - mrun[rr]);
        lrun[rr] += pr;
        lds_write_b16((char*)&Plds[w][4 * g + rr][nt * 16 + r], pr);
      }
    bx8 pa0 = lds_read_b128((char*)&Plds[w][r][g * 8]);       // after its 8 writes
    #pragma unroll
    for (int nt = 2; nt < 4; nt++)
      #pragma unroll
      for (int rr = 0; rr < 4; rr++) {
        float pr = __expf(sc[nt][rr] - mrun[rr]);
        lrun[rr] += pr;
        lds_write_b16((char*)&Plds[w][4 * g + rr][nt * 16 + r], pr);
      }
    bx8 pa1 = lds_read_b128((char*)&Plds[w][r][32 + g * 8]);
    LGKM(9);    // pa0 complete (8 writes + pa1 remain)
    #pragma unroll
    for (int dt = 0; dt < 8; dt++) of[dt] = mfma16(pa0, vf0[dt], of[dt]);
    LGKM(0);    // pa1 complete
    #pragma unroll
    for (int dt = 0; dt < 8; dt++) of[dt] = mfma16(pa1, vf1[dt], of[dt]);
    __builtin_amdgcn_s_barrier();                          // all waves done reading cur
    cur ^= 1;
  }
  #pragma unroll
  for (int off = 1; off < 16; off <<= 1)
    #pragma unroll
    for (int rr = 0; rr < 4; rr++) lrun[rr] += __shfl_xor(lrun[rr], off);
  float li[4];
  #pragma unroll
  for (int rr = 0; rr < 4; rr++) li[rr] = 1.0f / lrun[rr];
  #pragma unroll
  for (int dt = 0; dt < 8; dt++)
    #pragma unroll
    for (int rr = 0; rr < 4; rr++)
      O[(size_t)(qr0 + 4 * g + rr) * H_ + h * HD_ + dt * 16 + r] = (bf16_t)(of[dt][rr] * li[rr]);
}

// ---------------- host-side launch ----------------
extern "C" void kernel_launch(void* const* d_in, const int* in_sizes, int n_in,
                              void* d_out, int out_size, void* d_ws, size_t ws_size,
                              hipStream_t stream) {
  const float* embeds = (const float*)d_in[0];
  const int*   pos    = (const int*)d_in[1];
  const float* past_k = (const float*)d_in[2];
  const float* past_v = (const float*)d_in[3];
  const float* ln1    = (const float*)d_in[4];
  const float* wq     = (const float*)d_in[5];
  const float* bq     = (const float*)d_in[6];
  const float* wk     = (const float*)d_in[7];
  const float* bk     = (const float*)d_in[8];
  const float* wv     = (const float*)d_in[9];
  const float* bv     = (const float*)d_in[10];
  const float* wo     = (const float*)d_in[11];
  const float* ln2    = (const float*)d_in[12];
  const float* wg     = (const float*)d_in[13];
  const float* wu     = (const float*)d_in[14];
  const float* wd     = (const float*)d_in[15];
  const float* normw  = (const float*)d_in[16];

  char* wsp = (char*)d_ws;
  auto take = [&](size_t n) { char* p = wsp; wsp += (n + 255) & ~(size_t)255; return (void*)p; };
  float*  cos_t  = (float*)take((size_t)S_ * 64 * 4);
  float*  sin_t  = (float*)take((size_t)S_ * 64 * 4);
  float*  cbias  = (float*)take((size_t)L_ * QKVN_ * 4);
  float*  hidden = (float*)take((size_t)S_ * H_ * 4);
  bf16_t* hnorm  = (bf16_t*)take((size_t)S_ * H_ * 2);
  bf16_t* qkv    = (bf16_t*)take((size_t)S_ * QKVN_ * 2);
  bf16_t* qrope  = (bf16_t*)take((size_t)NH_ * S_ * HD_ * 2);
  bf16_t* kcache = (bf16_t*)take((size_t)NKV_ * T_ * HD_ * 2);
  bf16_t* vtr    = (bf16_t*)take((size_t)NKV_ * HD_ * T_ * 2);
  bf16_t* attno  = (bf16_t*)take((size_t)S_ * H_ * 2);
  bf16_t* gateb  = (bf16_t*)take((size_t)S_ * FF_ * 2);
  bf16_t* hgb    = (bf16_t*)take((size_t)S_ * FF_ * 2);
  bf16_t* wT     = (bf16_t*)take((size_t)FF_ * H_ * 2);   // max: 5632x2048 bf16

  float* out_h = (float*)d_out;

  k_rope_tables<<<256, 256, 0, stream>>>(pos, cos_t, sin_t);
  k_cbias<<<(L_ * QKVN_ + 255) / 256, 256, 0, stream>>>(bq, bk, bv, cbias);
  k_copy4<<<(S_ * H_ / 4 + 255) / 256, 256, 0, stream>>>(embeds, hidden, S_ * H_ / 4);

  for (int l = 0; l < L_; l++) {
    const float* wq_l = wq + (size_t)l * H_ * (NH_ * HD_);
    const float* wk_l = wk + (size_t)l * H_ * (NKV_ * HD_);
    const float* wv_l = wv + (size_t)l * H_ * (NKV_ * HD_);
    const float* wo_l = wo + (size_t)l * (NH_ * HD_) * H_;
    const float* wg_l = wg + (size_t)l * H_ * FF_;
    const float* wu_l = wu + (size_t)l * H_ * FF_;
    const float* wd_l = wd + (size_t)l * FF_ * H_;
    const float* pk_in = past_k + (size_t)l * NKV_ * P_ * HD_;
    const float* pv_in = past_v + (size_t)l * NKV_ * P_ * HD_;
    float* pk_out = out_h + (size_t)S_ * H_ + (size_t)l * 2 * NKV_ * T_ * HD_;
    float* pv_out = pk_out + (size_t)NKV_ * T_ * HD_;

    // attn input norm
    k_rmsnorm<1><<<S_, 256, 0, stream>>>(hidden, ln1 + (size_t)l * H_, hnorm);
    // fused QKV projection: Bt = [wq^T | wk^T | wv^T] as [2560][2048]
    k_transpose_w<<<dim3(32, 32), 256, 0, stream>>>(wq_l, wT, H_, NH_ * HD_);
    k_transpose_w<<<dim3(4, 32), 256, 0, stream>>>(wk_l, wT + (size_t)KOFF_ * H_, H_, NKV_ * HD_);
    k_transpose_w<<<dim3(4, 32), 256, 0, stream>>>(wv_l, wT + (size_t)VOFF_ * H_, H_, NKV_ * HD_);
    k_gemm<1, 1, 0, 0, 1><<<(QKVN_ / 128) * (S_ / 64), 256, 0, stream>>>(
        hnorm, wT, cbias + (size_t)l * QKVN_, nullptr, nullptr, qkv, S_, QKVN_, H_, H_, S_ / 64);
    // rope + cache build (also writes f32 present outputs)
    k_rope_q<<<(S_ * NH_ * 64) / 256, 256, 0, stream>>>(qkv, cos_t, sin_t, qrope);
    k_build_k<<<(NKV_ * T_ * 64) / 256, 256, 0, stream>>>(qkv, pk_in, cos_t, sin_t, kcache, pk_out);
    k_build_vt<<<dim3(T_ / 64, HD_ / 64, NKV_), 256, 0, stream>>>(qkv, pv_in, vtr, pv_out);
    // attention (balanced 1-D grid: complementary chunks per CU)
    k_attn<<<512, 128, 0, stream>>>(qrope, kcache, vtr, attno);
    // output projection: split-K=2 atomic into hidden (holds residual)
    k_transpose_w<<<dim3(32, 32), 256, 0, stream>>>(wo_l, wT, NH_ * HD_, H_);
    k_gemm<0, 0, 0, 0, 2><<<2 * (H_ / 128) * (S_ / 64), 256, 0, stream>>>(
        attno, wT, nullptr, nullptr, nullptr, hidden, S_, H_, NH_ * HD_, (NH_ * HD_) / 2, S_ / 64);
    // MLP: 128x128 GEMMs — gate, up(+fused silu*gate), split-K down
    k_rmsnorm<1><<<S_, 256, 0, stream>>>(hidden, ln2 + (size_t)l * H_, hnorm);
    k_transpose_w<<<dim3(88, 32), 256, 0, stream>>>(wg_l, wT, H_, FF_);
    k_gemm_big<1, 0, 1><<<(FF_ / 128) * (S_ / 128), 256, 0, stream>>>(
        hnorm, wT, nullptr, gateb, S_, FF_, H_, H_, S_ / 128);
    k_transpose_w<<<dim3(88, 32), 256, 0, stream>>>(wu_l, wT, H_, FF_);
    k_gemm_big<1, 1, 1><<<(FF_ / 128) * (S_ / 128), 256, 0, stream>>>(
        hnorm, wT, gateb, hgb, S_, FF_, H_, H_, S_ / 128);
    k_transpose_w<<<dim3(32, 88), 256, 0, stream>>>(wd_l, wT, FF_, H_);
    // down: hidden already holds residual; 2 splits atomic-add their partials
    k_gemm_big<0, 0, 2><<<2 * (H_ / 128) * (S_ / 128), 256, 0, stream>>>(
        hgb, wT, nullptr, hidden, S_, H_, FF_, FF_ / 2, S_ / 128);
  }
  k_rmsnorm<0><<<S_, 256, 0, stream>>>(hidden, normw, out_h);
}

// Round 20
// 544.449 us; speedup vs baseline: 1.0264x; 1.0264x over previous
//
#include <hip/hip_runtime.h>

#define L_ 2
#define H_ 2048
#define NH_ 16
#define NKV_ 2
#define HD_ 128
#define S_ 1024
#define P_ 1024
#define T_ 2048
#define FF_ 5632
#define QKVN_ 2560   // NH*HD + 2*NKV*HD
#define KOFF_ 2048
#define VOFF_ 2304

#define EPS_ 1e-6f
#define SCALE_ 0.08838834764831845f   // 1/sqrt(128)
#define DEFER_THR_ 8.0f

typedef __bf16 bf16_t;
typedef unsigned int u32;
typedef __bf16 bx8 __attribute__((ext_vector_type(8)));
typedef __bf16 bx4 __attribute__((ext_vector_type(4)));
typedef float  fx4 __attribute__((ext_vector_type(4)));

__device__ __forceinline__ fx4 mfma16(bx8 a, bx8 b, fx4 c) {
  return __builtin_amdgcn_mfma_f32_16x16x32_bf16(a, b, c, 0, 0, 0);
}

// global->LDS direct, 16B per lane; lds dest = wave-uniform base + lane*16
#define GLL16(gsrc, ldst) __builtin_amdgcn_global_load_lds( \
    (__attribute__((address_space(1))) void*)(gsrc),        \
    (__attribute__((address_space(3))) void*)(ldst), 16, 0, 0)

// opaque LDS ops: compiler cannot attach vmem (global_load_lds) dependencies,
// so it cannot insert a hidden vmcnt(0) before them. Caller must lgkmcnt-fence.
__device__ __forceinline__ bx8 lds_read_b128(char* p) {
  u32 a = (u32)(uintptr_t)(__attribute__((address_space(3))) void*)p;
  bx8 d;
  asm volatile("ds_read_b128 %0, %1" : "=v"(d) : "v"(a));
  return d;
}
__device__ __forceinline__ void lds_write_b16(char* p, float v) {
  u32 a = (u32)(uintptr_t)(__attribute__((address_space(3))) void*)p;
  bf16_t b = (bf16_t)v;
  u32 d = (u32)__builtin_bit_cast(unsigned short, b);
  asm volatile("ds_write_b16 %0, %1" :: "v"(a), "v"(d));
}

#define LGKM(n) asm volatile("s_waitcnt lgkmcnt(" #n ")" ::: "memory"); __builtin_amdgcn_sched_barrier(0)

// bijective XCD swizzle (m204): consecutive work-ids land on the same XCD
__device__ __forceinline__ int xcd_swizzle(int orig, int nwg) {
  int q = nwg >> 3, r = nwg & 7;
  int xcd = orig & 7, lid = orig >> 3;
  return (xcd < r ? xcd * (q + 1) : r * (q + 1) + (xcd - r) * q) + lid;
}

// ---------------- RoPE tables ----------------
__global__ void k_rope_tables(const int* __restrict__ pos, float* __restrict__ ct, float* __restrict__ st) {
  int i = blockIdx.x * 256 + threadIdx.x;
  if (i >= S_ * 64) return;
  int s = i >> 6, d = i & 63;
  float p = (float)pos[s];
  float inv = expf(-(float)(2 * d) * (13.815510557964274f / 128.0f));  // theta=1e6
  float f = p * inv;
  ct[i] = cosf(f);
  st[i] = sinf(f);
}

__global__ void k_copy4(const float* __restrict__ in, float* __restrict__ out, int n4) {
  int i = blockIdx.x * 256 + threadIdx.x;
  if (i < n4) ((fx4*)out)[i] = ((const fx4*)in)[i];
}

// concat bias: [L][2560] = bq | bk | bv
__global__ void k_cbias(const float* __restrict__ bq, const float* __restrict__ bk,
                        const float* __restrict__ bv, float* __restrict__ cb) {
  int i = blockIdx.x * 256 + threadIdx.x;
  if (i >= L_ * QKVN_) return;
  int l = i / QKVN_, j = i % QKVN_;
  float v;
  if (j < KOFF_)      v = bq[l * KOFF_ + j];
  else if (j < VOFF_) v = bk[l * (NKV_ * HD_) + j - KOFF_];
  else                v = bv[l * (NKV_ * HD_) + j - VOFF_];
  cb[i] = v;
}

// ---------------- RMSNorm (one block per row) ----------------
template<int OUTBF>
__global__ __launch_bounds__(256) void k_rmsnorm(const float* __restrict__ x, const float* __restrict__ w,
                                                 void* __restrict__ y) {
  int row = blockIdx.x, tid = threadIdx.x;
  const fx4* xr = (const fx4*)(x + (size_t)row * H_);
  fx4 v0 = xr[tid], v1 = xr[tid + 256];
  float ss = v0[0]*v0[0] + v0[1]*v0[1] + v0[2]*v0[2] + v0[3]*v0[3]
           + v1[0]*v1[0] + v1[1]*v1[1] + v1[2]*v1[2] + v1[3]*v1[3];
  #pragma unroll
  for (int off = 32; off > 0; off >>= 1) ss += __shfl_xor(ss, off);
  __shared__ float red[4];
  if ((tid & 63) == 0) red[tid >> 6] = ss;
  __syncthreads();
  float tot = red[0] + red[1] + red[2] + red[3];
  float rs = rsqrtf(tot * (1.0f / H_) + EPS_);
  const fx4* wr_ = (const fx4*)w;
  fx4 w0 = wr_[tid], w1 = wr_[tid + 256];
  if (OUTBF) {
    bf16_t* yb = (bf16_t*)y + (size_t)row * H_;
    bx4 o0, o1;
    #pragma unroll
    for (int i = 0; i < 4; i++) { o0[i] = (bf16_t)(v0[i] * rs * w0[i]); o1[i] = (bf16_t)(v1[i] * rs * w1[i]); }
    *(bx4*)&yb[tid * 4] = o0;
    *(bx4*)&yb[(tid + 256) * 4] = o1;
  } else {
    float* yf = (float*)y + (size_t)row * H_;
    fx4 o0, o1;
    #pragma unroll
    for (int i = 0; i < 4; i++) { o0[i] = v0[i] * rs * w0[i]; o1[i] = v1[i] * rs * w1[i]; }
    *(fx4*)&yf[tid * 4] = o0;
    *(fx4*)&yf[(tid + 256) * 4] = o1;
  }
}

// ---------------- weight transpose+convert: out[C][R] = bf16(in[R][C]^T) ----------------
__global__ __launch_bounds__(256) void k_transpose_w(const float* __restrict__ in, bf16_t* __restrict__ out,
                                                     int R, int C) {
  __shared__ __attribute__((aligned(16))) float Tt[64 * 68];
  int tid = threadIdx.x;
  int c0 = blockIdx.x * 64, r0 = blockIdx.y * 64;
  #pragma unroll
  for (int j = 0; j < 4; j++) {
    int c = j * 256 + tid;
    int row = c >> 4, col = (c & 15) * 4;
    *(fx4*)&Tt[row * 68 + col] = *(const fx4*)&in[(size_t)(r0 + row) * C + c0 + col];
  }
  __syncthreads();
  #pragma unroll
  for (int j = 0; j < 2; j++) {
    int c = j * 256 + tid;
    int n = c >> 3, ko = (c & 7) * 8;
    bx8 o;
    #pragma unroll
    for (int i = 0; i < 8; i++) o[i] = (bf16_t)Tt[(ko + i) * 68 + n];
    *(bx8*)&out[(size_t)(c0 + n) * R + r0 + ko] = o;
  }
}

// ---------------- GEMM 64x128: C[M,N] = A[M,K](bf16) * Bt[N,K]^T ----------------
// 2-buffer depth-1 pipeline (48KB LDS), counted vmcnt(6), raw s_barrier,
// opaque asm ds_read_b128, split-lgkm(6/0) + setprio.
// SPLIT>1: each split does kLen of K and atomicAdds f32 partials into out.
template<int OUTBF, int HASB, int HASR, int HASG, int SPLIT>
__global__ __launch_bounds__(256) void k_gemm(const bf16_t* __restrict__ A, const bf16_t* __restrict__ Bt,
                                              const float* __restrict__ bias, const float* __restrict__ res,
                                              const bf16_t* __restrict__ gmul,
                                              void* __restrict__ out, int M, int N, int lda, int kLen, int gy) {
  __shared__ __attribute__((aligned(16))) bf16_t sA[2][64 * 64];
  __shared__ __attribute__((aligned(16))) bf16_t sB[2][128 * 64];
  int tid = threadIdx.x;
  int w = tid >> 6, lane = tid & 63, g = lane >> 4, r = lane & 15;
  int wr = w >> 1, wc = w & 1;
  int swzid = xcd_swizzle((int)blockIdx.x, (int)gridDim.x);
  int per = (int)gridDim.x / SPLIT;
  int sp = swzid / per;
  int rem = swzid - sp * per;
  int m0 = (rem % gy) * 64;
  int n0 = (rem / gy) * 128;
  A  += (size_t)sp * kLen;
  Bt += (size_t)sp * kLen;
  fx4 acc[2][4] = {};
  int swz = (r & 7) << 4;
  int col0 = (g * 16) ^ swz;
  int col1 = (64 + g * 16) ^ swz;
  int wbase = (tid & ~63) * 16;
  int nk = kLen >> 6;

  auto STAGE = [&](int buf, int k0) {
    #pragma unroll
    for (int j = 0; j < 2; j++) {
      int d = (j * 256 + tid) * 16;
      int row = d >> 7;
      int inrow = (d & 127) ^ ((row & 7) << 4);
      GLL16((const char*)(A + (size_t)(m0 + row) * lda + k0) + inrow,
            (char*)&sA[buf][0] + j * 4096 + wbase);
    }
    #pragma unroll
    for (int j = 0; j < 4; j++) {
      int d = (j * 256 + tid) * 16;
      int row = d >> 7;
      int inrow = (d & 127) ^ ((row & 7) << 4);
      GLL16((const char*)(Bt + (size_t)(n0 + row) * lda + k0) + inrow,
            (char*)&sB[buf][0] + j * 4096 + wbase);
    }
  };

  STAGE(0, 0);                                     // 6 outstanding
  int cur = 0;
  for (int t = 0; t < nk; t++) {
    if (t + 1 < nk) {
      STAGE(cur ^ 1, (t + 1) << 6);                // 12 outstanding
      asm volatile("s_waitcnt vmcnt(6)" ::: "memory");  // cur's loads landed
    } else {
      asm volatile("s_waitcnt vmcnt(0)" ::: "memory");
    }
    __builtin_amdgcn_s_barrier();                  // all waves' cur-stage visible
    __builtin_amdgcn_sched_barrier(0);
    char* pa = (char*)&sA[cur][0] + (wr * 32 + r) * 128;
    char* pb = (char*)&sB[cur][0] + (wc * 64 + r) * 128;
    bx8 fa[2][2], fb[4][2];
    fa[0][0] = lds_read_b128(pa + col0);
    fa[1][0] = lds_read_b128(pa + 2048 + col0);
    #pragma unroll
    for (int n = 0; n < 4; n++) fb[n][0] = lds_read_b128(pb + n * 2048 + col0);
    fa[0][1] = lds_read_b128(pa + col1);
    fa[1][1] = lds_read_b128(pa + 2048 + col1);
    #pragma unroll
    for (int n = 0; n < 4; n++) fb[n][1] = lds_read_b128(pb + n * 2048 + col1);
    LGKM(6);                                       // col0 set complete
    __builtin_amdgcn_s_setprio(1);
    #pragma unroll
    for (int n = 0; n < 4; n++) {
      acc[0][n] = mfma16(fa[0][0], fb[n][0], acc[0][n]);
      acc[1][n] = mfma16(fa[1][0], fb[n][0], acc[1][n]);
    }
    __builtin_amdgcn_s_setprio(0);
    LGKM(0);                                       // col1 set complete
    __builtin_amdgcn_s_setprio(1);
    #pragma unroll
    for (int n = 0; n < 4; n++) {
      acc[0][n] = mfma16(fa[0][1], fb[n][1], acc[0][n]);
      acc[1][n] = mfma16(fa[1][1], fb[n][1], acc[1][n]);
    }
    __builtin_amdgcn_s_setprio(0);
    if (t + 1 < nk) {
      __builtin_amdgcn_s_barrier();                // reads done before buf reuse
      __builtin_amdgcn_sched_barrier(0);
    }
    cur ^= 1;
  }
  #pragma unroll
  for (int m = 0; m < 2; m++)
    #pragma unroll
    for (int n = 0; n < 4; n++) {
      int col = n0 + wc * 64 + n * 16 + r;
      #pragma unroll
      for (int rr = 0; rr < 4; rr++) {
        int row = m0 + wr * 32 + m * 16 + 4 * g + rr;
        float v = acc[m][n][rr];
        if (SPLIT > 1) {
          atomicAdd(&((float*)out)[(size_t)row * N + col], v);
        } else {
          if (HASB) v += bias[col];
          if (HASR) v += res[(size_t)row * N + col];
          if (HASG) {
            float x = (float)gmul[(size_t)row * N + col];
            v = (x / (1.0f + __expf(-x))) * v;
          }
          if (OUTBF) ((bf16_t*)out)[(size_t)row * N + col] = (bf16_t)v;
          else       ((float*)out)[(size_t)row * N + col] = v;
        }
      }
    }
}

// ---------------- fused gate+up GEMM + SiLU: out = silu(A*Bg^T) * (A*Bu^T) ----------------
// 64x128 tile, 2-buffer depth-1 pipeline (80KB LDS), counted vmcnt(10),
// opaque reads, split-lgkm(10/0) + setprio; 32 MFMA per barrier-pair.
__global__ __launch_bounds__(256) void k_gemm_gu(const bf16_t* __restrict__ A, const bf16_t* __restrict__ Bg,
                                                 const bf16_t* __restrict__ Bu, bf16_t* __restrict__ out,
                                                 int M, int N, int lda, int gy) {
  __shared__ __attribute__((aligned(16))) bf16_t sA[2][64 * 64];
  __shared__ __attribute__((aligned(16))) bf16_t sBg[2][128 * 64];
  __shared__ __attribute__((aligned(16))) bf16_t sBu[2][128 * 64];
  int tid = threadIdx.x;
  int w = tid >> 6, lane = tid & 63, g = lane >> 4, r = lane & 15;
  int wr = w >> 1, wc = w & 1;
  int swzid = xcd_swizzle((int)blockIdx.x, (int)gridDim.x);
  int m0 = (swzid % gy) * 64;
  int n0 = (swzid / gy) * 128;
  fx4 accg[2][4] = {}, accu[2][4] = {};
  int swz = (r & 7) << 4;
  int col0 = (g * 16) ^ swz;
  int col1 = (64 + g * 16) ^ swz;
  int wbase = (tid & ~63) * 16;
  int nk = lda >> 6;   // K == lda here

  auto STAGE = [&](int buf, int k0) {
    #pragma unroll
    for (int j = 0; j < 2; j++) {
      int d = (j * 256 + tid) * 16;
      int row = d >> 7;
      int inrow = (d & 127) ^ ((row & 7) << 4);
      GLL16((const char*)(A + (size_t)(m0 + row) * lda + k0) + inrow,
            (char*)&sA[buf][0] + j * 4096 + wbase);
    }
    #pragma unroll
    for (int j = 0; j < 4; j++) {
      int d = (j * 256 + tid) * 16;
      int row = d >> 7;
      int inrow = (d & 127) ^ ((row & 7) << 4);
      GLL16((const char*)(Bg + (size_t)(n0 + row) * lda + k0) + inrow,
            (char*)&sBg[buf][0] + j * 4096 + wbase);
    }
    #pragma unroll
    for (int j = 0; j < 4; j++) {
      int d = (j * 256 + tid) * 16;
      int row = d >> 7;
      int inrow = (d & 127) ^ ((row & 7) << 4);
      GLL16((const char*)(Bu + (size_t)(n0 + row) * lda + k0) + inrow,
            (char*)&sBu[buf][0] + j * 4096 + wbase);
    }
  };

  STAGE(0, 0);                                     // 10 outstanding
  int cur = 0;
  for (int t = 0; t < nk; t++) {
    if (t + 1 < nk) {
      STAGE(cur ^ 1, (t + 1) << 6);                // 20 outstanding
      asm volatile("s_waitcnt vmcnt(10)" ::: "memory");  // cur's 10 landed
    } else {
      asm volatile("s_waitcnt vmcnt(0)" ::: "memory");
    }
    __builtin_amdgcn_s_barrier();
    __builtin_amdgcn_sched_barrier(0);
    char* pa = (char*)&sA[cur][0] + (wr * 32 + r) * 128;
    char* pg = (char*)&sBg[cur][0] + (wc * 64 + r) * 128;
    char* pu = (char*)&sBu[cur][0] + (wc * 64 + r) * 128;
    bx8 fa[2][2], fg[4][2], fu[4][2];
    // col0 set: 10 reads, then col1 set: 10 reads (DS completes in order)
    fa[0][0] = lds_read_b128(pa + col0);
    fa[1][0] = lds_read_b128(pa + 2048 + col0);
    #pragma unroll
    for (int n = 0; n < 4; n++) fg[n][0] = lds_read_b128(pg + n * 2048 + col0);
    #pragma unroll
    for (int n = 0; n < 4; n++) fu[n][0] = lds_read_b128(pu + n * 2048 + col0);
    fa[0][1] = lds_read_b128(pa + col1);
    fa[1][1] = lds_read_b128(pa + 2048 + col1);
    #pragma unroll
    for (int n = 0; n < 4; n++) fg[n][1] = lds_read_b128(pg + n * 2048 + col1);
    #pragma unroll
    for (int n = 0; n < 4; n++) fu[n][1] = lds_read_b128(pu + n * 2048 + col1);
    LGKM(10);                                      // col0 set complete
    __builtin_amdgcn_s_setprio(1);
    #pragma unroll
    for (int n = 0; n < 4; n++) {
      accg[0][n] = mfma16(fa[0][0], fg[n][0], accg[0][n]);
      accg[1][n] = mfma16(fa[1][0], fg[n][0], accg[1][n]);
      accu[0][n] = mfma16(fa[0][0], fu[n][0], accu[0][n]);
      accu[1][n] = mfma16(fa[1][0], fu[n][0], accu[1][n]);
    }
    __builtin_amdgcn_s_setprio(0);
    LGKM(0);                                       // col1 set complete
    __builtin_amdgcn_s_setprio(1);
    #pragma unroll
    for (int n = 0; n < 4; n++) {
      accg[0][n] = mfma16(fa[0][1], fg[n][1], accg[0][n]);
      accg[1][n] = mfma16(fa[1][1], fg[n][1], accg[1][n]);
      accu[0][n] = mfma16(fa[0][1], fu[n][1], accu[0][n]);
      accu[1][n] = mfma16(fa[1][1], fu[n][1], accu[1][n]);
    }
    __builtin_amdgcn_s_setprio(0);
    if (t + 1 < nk) {
      __builtin_amdgcn_s_barrier();
      __builtin_amdgcn_sched_barrier(0);
    }
    cur ^= 1;
  }
  #pragma unroll
  for (int m = 0; m < 2; m++)
    #pragma unroll
    for (int n = 0; n < 4; n++) {
      int col = n0 + wc * 64 + n * 16 + r;
      #pragma unroll
      for (int rr = 0; rr < 4; rr++) {
        int row = m0 + wr * 32 + m * 16 + 4 * g + rr;
        float x = accg[m][n][rr];
        float u = accu[m][n][rr];
        float s = x / (1.0f + __expf(-x));
        out[(size_t)row * N + col] = (bf16_t)(s * u);
      }
    }
}

// ---------------- RoPE on Q: qkv[S][2560] bf16 -> [NH][S][HD] bf16 ----------------
__global__ void k_rope_q(const bf16_t* __restrict__ qkv, const float* __restrict__ ct,
                         const float* __restrict__ st, bf16_t* __restrict__ qout) {
  int i = blockIdx.x * 256 + threadIdx.x;
  if (i >= S_ * NH_ * 64) return;
  int d = i & 63, h = (i >> 6) & 15, s = i >> 10;
  size_t ib = (size_t)s * QKVN_ + h * HD_;
  float x1 = (float)qkv[ib + d];
  float x2 = (float)qkv[ib + d + 64];
  float c = ct[s * 64 + d], sn = st[s * 64 + d];
  size_t ob = ((size_t)h * S_ + s) * HD_;
  qout[ob + d]      = (bf16_t)(x1 * c - x2 * sn);
  qout[ob + d + 64] = (bf16_t)(x2 * c + x1 * sn);
}

// ---------------- K: rope new keys + concat past -> bf16 [NKV][T][HD] + f32 present ----------------
__global__ void k_build_k(const bf16_t* __restrict__ qkv, const float* __restrict__ pastk,
                          const float* __restrict__ ct, const float* __restrict__ st,
                          bf16_t* __restrict__ kc, float* __restrict__ pk_out) {
  int i = blockIdx.x * 256 + threadIdx.x;
  if (i >= NKV_ * T_ * 64) return;
  int d = i & 63, t = (i >> 6) & (T_ - 1), kv = i >> 17;
  size_t cb = ((size_t)kv * T_ + t) * HD_;
  if (t < P_) {
    size_t pb = ((size_t)kv * P_ + t) * HD_;
    float a = pastk[pb + d], b = pastk[pb + d + 64];
    kc[cb + d] = (bf16_t)a; kc[cb + d + 64] = (bf16_t)b;
    pk_out[cb + d] = a;     pk_out[cb + d + 64] = b;
  } else {
    int s = t - P_;
    size_t ib = (size_t)s * QKVN_ + KOFF_ + kv * HD_;
    float x1 = (float)qkv[ib + d];
    float x2 = (float)qkv[ib + d + 64];
    float c = ct[s * 64 + d], sn = st[s * 64 + d];
    float k1 = x1 * c - x2 * sn, k2 = x2 * c + x1 * sn;
    kc[cb + d] = (bf16_t)k1; kc[cb + d + 64] = (bf16_t)k2;
    pk_out[cb + d] = k1;     pk_out[cb + d + 64] = k2;
  }
}

// ---------------- V: concat past+new -> VT bf16 [NKV][HD][T] + f32 present ----------------
__global__ __launch_bounds__(256) void k_build_vt(const bf16_t* __restrict__ qkv, const float* __restrict__ pastv,
                                                  bf16_t* __restrict__ vt, float* __restrict__ pv_out) {
  int t0 = blockIdx.x * 64, d0 = blockIdx.y * 64, kv = blockIdx.z;
  __shared__ __attribute__((aligned(16))) float Tt[64 * 68];
  int tid = threadIdx.x;
  if (t0 < P_) {
    #pragma unroll
    for (int j = 0; j < 4; j++) {
      int c = j * 256 + tid;
      int row = c >> 4, col = (c & 15) * 4;
      int t = t0 + row;
      fx4 v = *(const fx4*)&pastv[((size_t)kv * P_ + t) * HD_ + d0 + col];
      *(fx4*)&Tt[row * 68 + col] = v;
      *(fx4*)&pv_out[((size_t)kv * T_ + t) * HD_ + d0 + col] = v;
    }
  } else {
    #pragma unroll
    for (int j = 0; j < 4; j++) {
      int c = j * 256 + tid;
      int row = c >> 4, col = (c & 15) * 4;
      int t = t0 + row;
      bx4 b = *(const bx4*)&qkv[(size_t)(t - P_) * QKVN_ + VOFF_ + kv * HD_ + d0 + col];
      fx4 v;
      #pragma unroll
      for (int q = 0; q < 4; q++) v[q] = (float)b[q];
      *(fx4*)&Tt[row * 68 + col] = v;
      *(fx4*)&pv_out[((size_t)kv * T_ + t) * HD_ + d0 + col] = v;
    }
  }
  __syncthreads();
  #pragma unroll
  for (int j = 0; j < 2; j++) {
    int c = j * 256 + tid;
    int n = c >> 3, ko = (c & 7) * 8;
    bx8 o;
    #pragma unroll
    for (int i = 0; i < 8; i++) o[i] = (bf16_t)Tt[(ko + i) * 68 + n];
    *(bx8*)&vt[((size_t)kv * HD_ + d0 + n) * T_ + t0 + ko] = o;
  }
}

// ---------------- flash attention (stable 62us): balanced chunk mapping ----------------
__global__ __launch_bounds__(128) void k_attn(const bf16_t* __restrict__ Q, const bf16_t* __restrict__ Kc,
                                              const bf16_t* __restrict__ VT, bf16_t* __restrict__ O) {
  __shared__ __attribute__((aligned(16))) bf16_t Klds[2][64 * 128];
  __shared__ __attribute__((aligned(16))) bf16_t Vlds[2][128 * 64];
  __shared__ __attribute__((aligned(16))) bf16_t Plds[2][16][72];
  int tid = threadIdx.x;               // 0..127
  int w = tid >> 6, lane = tid & 63, g = lane >> 4, r = lane & 15;
  int b = blockIdx.x;                  // 0..511
  int half = b >> 8;                   // = kv
  int idx = b & 255;
  int cx = idx & 31;
  int chunk = half ? (31 - cx) : cx;   // complementary chunks land on same CU
  int h = (half << 3) | (idx >> 5);    // heads 0-7 (kv0) / 8-15 (kv1)
  int kv = half;
  int m0 = chunk * 32;
  int qr0 = m0 + w * 16;
  const bf16_t* qb = Q + ((size_t)h * S_ + qr0 + r) * HD_ + g * 8;
  bx8 qf[4];
  #pragma unroll
  for (int kc = 0; kc < 4; kc++) qf[kc] = *(const bx8*)(qb + kc * 32);
  fx4 of[8] = {};
  float mrun[4], lrun[4];
  #pragma unroll
  for (int i = 0; i < 4; i++) { mrun[i] = -1e30f; lrun[i] = 0.0f; }
  int lim = P_ + qr0 + 4 * g;
  int ntile = (P_ + m0 + 32 + 63) >> 6;
  const char* kg = (const char*)(Kc + (size_t)kv * T_ * HD_);
  const char* vg = (const char*)(VT + (size_t)kv * HD_ * T_);
  int wbase = (tid & ~63) * 16;        // w*1024

  auto STAGE = [&](int buf, int t0) {
    #pragma unroll
    for (int j = 0; j < 8; j++) {      // K: 64 rows x 256B = 16KB, 2KB/round
      int D = j * 2048 + tid * 16;
      int row = D >> 8, inrow = D & 255;
      const char* src = kg + (size_t)(t0 + row) * 256 + (inrow ^ ((row & 7) << 4));
      GLL16(src, (char*)&Klds[buf][0] + j * 2048 + wbase);
    }
    #pragma unroll
    for (int j = 0; j < 8; j++) {      // V^T: 128 rows x 128B = 16KB
      int D = j * 2048 + tid * 16;
      int row = D >> 7, inrow = D & 127;
      const char* src = vg + (size_t)row * 4096 + (size_t)t0 * 2 + (inrow ^ ((row & 7) << 4));
      GLL16(src, (char*)&Vlds[buf][0] + j * 2048 + wbase);
    }
  };

  STAGE(0, 0);
  asm volatile("s_waitcnt vmcnt(0)" ::: "memory");
  __builtin_amdgcn_s_barrier();
  __builtin_amdgcn_sched_barrier(0);
  int cur = 0;
  for (int t = 0; t < ntile; t++) {
    int t0 = t * 64;
    if (t + 1 < ntile) {
      STAGE(cur ^ 1, t0 + 64);                             // issue next tile (16 vm ops)
      asm volatile("s_waitcnt vmcnt(16)" ::: "memory");    // cur's stage landed
    } else {
      asm volatile("s_waitcnt vmcnt(0)" ::: "memory");
    }
    __builtin_amdgcn_s_barrier();                          // all waves' cur-stage visible
    __builtin_amdgcn_sched_barrier(0);
    // ---- QK^T: 16 opaque ds_reads, counted lgkm, interleaved MFMAs ----
    char* kb = (char*)&Klds[cur][0];
    char* vb = (char*)&Vlds[cur][0];
    bx8 kf[4][4];
    #pragma unroll
    for (int nt = 0; nt < 4; nt++) {
      int row = nt * 16 + r;
      char* kr = kb + row * 256;
      int sz = (row & 7) << 4;
      #pragma unroll
      for (int kc = 0; kc < 4; kc++)
        kf[nt][kc] = lds_read_b128(kr + (((kc * 32 + g * 8) * 2) ^ sz));
    }
    fx4 sc[4] = {};
    LGKM(12);
    #pragma unroll
    for (int kc = 0; kc < 4; kc++) sc[0] = mfma16(qf[kc], kf[0][kc], sc[0]);
    LGKM(8);
    #pragma unroll
    for (int kc = 0; kc < 4; kc++) sc[1] = mfma16(qf[kc], kf[1][kc], sc[1]);
    LGKM(4);
    #pragma unroll
    for (int kc = 0; kc < 4; kc++) sc[2] = mfma16(qf[kc], kf[2][kc], sc[2]);
    LGKM(0);
    #pragma unroll
    for (int kc = 0; kc < 4; kc++) sc[3] = mfma16(qf[kc], kf[3][kc], sc[3]);
    // ---- issue all 16 V reads; latency hides under softmax VALU ----
    bx8 vf0[8], vf1[8];
    #pragma unroll
    for (int dt = 0; dt < 8; dt++) {
      int row = dt * 16 + r;
      vf0[dt] = lds_read_b128(vb + row * 128 + (((g * 8) * 2) ^ ((row & 7) << 4)));
    }
    #pragma unroll
    for (int dt = 0; dt < 8; dt++) {
      int row = dt * 16 + r;
      vf1[dt] = lds_read_b128(vb + row * 128 + (((32 + g * 8) * 2) ^ ((row & 7) << 4)));
    }
    // ---- softmax (defer-max) ----
    float lm[4] = {-1e30f, -1e30f, -1e30f, -1e30f};
    #pragma unroll
    for (int nt = 0; nt < 4; nt++)
      #pragma unroll
      for (int rr = 0; rr < 4; rr++) {
        int key = t0 + nt * 16 + r;
        float sv = sc[nt][rr] * SCALE_;
        sv = (key > lim + rr) ? -1e30f : sv;
        sc[nt][rr] = sv;
        lm[rr] = fmaxf(lm[rr], sv);
      }
    int ok = (lm[0] <= mrun[0] + DEFER_THR_) & (lm[1] <= mrun[1] + DEFER_THR_) &
             (lm[2] <= mrun[2] + DEFER_THR_) & (lm[3] <= mrun[3] + DEFER_THR_);
    if (!__all(ok)) {
      float av[4];
      #pragma unroll
      for (int off = 1; off < 16; off <<= 1)
        #pragma unroll
        for (int rr = 0; rr < 4; rr++) lm[rr] = fmaxf(lm[rr], __shfl_xor(lm[rr], off));
      #pragma unroll
      for (int rr = 0; rr < 4; rr++) {
        float mn = fmaxf(mrun[rr], lm[rr]);
        av[rr] = __expf(mrun[rr] - mn);
        mrun[rr] = mn;
        lrun[rr] *= av[rr];
      }
      #pragma unroll
      for (int f = 0; f < 8; f++)
        #pragma unroll
        for (int rr = 0; rr < 4; rr++) of[f][rr] *= av[rr];
    }
    // P writes: cols 0-31 then pa0 read; cols 32-63 then pa1
    #pragma unroll
    for (int nt = 0; nt < 2; nt++)
      #pragma unroll
      for (int rr = 0; rr < 4; rr++) {
        float pr = __expf(sc[nt][rr] - mrun[rr]);
        lrun[rr] += pr;
        lds_write_b16((char*)&Plds[w][4 * g + rr][nt * 16 + r], pr);
      }
    bx8 pa0 = lds_read_b128((char*)&Plds[w][r][g * 8]);
    #pragma unroll
    for (int nt = 2; nt < 4; nt++)
      #pragma unroll
      for (int rr = 0; rr < 4; rr++) {
        float pr = __expf(sc[nt][rr] - mrun[rr]);
        lrun[rr] += pr;
        lds_write_b16((char*)&Plds[w][4 * g + rr][nt * 16 + r], pr);
      }
    bx8 pa1 = lds_read_b128((char*)&Plds[w][r][32 + g * 8]);
    LGKM(9);    // pa0 complete (8 writes + pa1 remain)
    #pragma unroll
    for (int dt = 0; dt < 8; dt++) of[dt] = mfma16(pa0, vf0[dt], of[dt]);
    LGKM(0);    // pa1 complete
    #pragma unroll
    for (int dt = 0; dt < 8; dt++) of[dt] = mfma16(pa1, vf1[dt], of[dt]);
    __builtin_amdgcn_s_barrier();                          // all waves done reading cur
    cur ^= 1;
  }
  #pragma unroll
  for (int off = 1; off < 16; off <<= 1)
    #pragma unroll
    for (int rr = 0; rr < 4; rr++) lrun[rr] += __shfl_xor(lrun[rr], off);
  float li[4];
  #pragma unroll
  for (int rr = 0; rr < 4; rr++) li[rr] = 1.0f / lrun[rr];
  #pragma unroll
  for (int dt = 0; dt < 8; dt++)
    #pragma unroll
    for (int rr = 0; rr < 4; rr++)
      O[(size_t)(qr0 + 4 * g + rr) * H_ + h * HD_ + dt * 16 + r] = (bf16_t)(of[dt][rr] * li[rr]);
}

// ---------------- host-side launch ----------------
extern "C" void kernel_launch(void* const* d_in, const int* in_sizes, int n_in,
                              void* d_out, int out_size, void* d_ws, size_t ws_size,
                              hipStream_t stream) {
  const float* embeds = (const float*)d_in[0];
  const int*   pos    = (const int*)d_in[1];
  const float* past_k = (const float*)d_in[2];
  const float* past_v = (const float*)d_in[3];
  const float* ln1    = (const float*)d_in[4];
  const float* wq     = (const float*)d_in[5];
  const float* bq     = (const float*)d_in[6];
  const float* wk     = (const float*)d_in[7];
  const float* bk     = (const float*)d_in[8];
  const float* wv     = (const float*)d_in[9];
  const float* bv     = (const float*)d_in[10];
  const float* wo     = (const float*)d_in[11];
  const float* ln2    = (const float*)d_in[12];
  const float* wg     = (const float*)d_in[13];
  const float* wu     = (const float*)d_in[14];
  const float* wd     = (const float*)d_in[15];
  const float* normw  = (const float*)d_in[16];

  char* wsp = (char*)d_ws;
  auto take = [&](size_t n) { char* p = wsp; wsp += (n + 255) & ~(size_t)255; return (void*)p; };
  float*  cos_t  = (float*)take((size_t)S_ * 64 * 4);
  float*  sin_t  = (float*)take((size_t)S_ * 64 * 4);
  float*  cbias  = (float*)take((size_t)L_ * QKVN_ * 4);
  float*  hidden = (float*)take((size_t)S_ * H_ * 4);
  bf16_t* hnorm  = (bf16_t*)take((size_t)S_ * H_ * 2);
  bf16_t* qkv    = (bf16_t*)take((size_t)S_ * QKVN_ * 2);
  bf16_t* qrope  = (bf16_t*)take((size_t)NH_ * S_ * HD_ * 2);
  bf16_t* kcache = (bf16_t*)take((size_t)NKV_ * T_ * HD_ * 2);
  bf16_t* vtr    = (bf16_t*)take((size_t)NKV_ * HD_ * T_ * 2);
  bf16_t* attno  = (bf16_t*)take((size_t)S_ * H_ * 2);
  bf16_t* hgb    = (bf16_t*)take((size_t)S_ * FF_ * 2);
  bf16_t* wT     = (bf16_t*)take((size_t)FF_ * H_ * 2);   // 23 MB (gate / qkv / wo / down)
  bf16_t* wTu    = (bf16_t*)take((size_t)FF_ * H_ * 2);   // 23 MB (up)

  float* out_h = (float*)d_out;

  k_rope_tables<<<256, 256, 0, stream>>>(pos, cos_t, sin_t);
  k_cbias<<<(L_ * QKVN_ + 255) / 256, 256, 0, stream>>>(bq, bk, bv, cbias);
  k_copy4<<<(S_ * H_ / 4 + 255) / 256, 256, 0, stream>>>(embeds, hidden, S_ * H_ / 4);

  for (int l = 0; l < L_; l++) {
    const float* wq_l = wq + (size_t)l * H_ * (NH_ * HD_);
    const float* wk_l = wk + (size_t)l * H_ * (NKV_ * HD_);
    const float* wv_l = wv + (size_t)l * H_ * (NKV_ * HD_);
    const float* wo_l = wo + (size_t)l * (NH_ * HD_) * H_;
    const float* wg_l = wg + (size_t)l * H_ * FF_;
    const float* wu_l = wu + (size_t)l * H_ * FF_;
    const float* wd_l = wd + (size_t)l * FF_ * H_;
    const float* pk_in = past_k + (size_t)l * NKV_ * P_ * HD_;
    const float* pv_in = past_v + (size_t)l * NKV_ * P_ * HD_;
    float* pk_out = out_h + (size_t)S_ * H_ + (size_t)l * 2 * NKV_ * T_ * HD_;
    float* pv_out = pk_out + (size_t)NKV_ * T_ * HD_;

    // attn input norm
    k_rmsnorm<1><<<S_, 256, 0, stream>>>(hidden, ln1 + (size_t)l * H_, hnorm);
    // fused QKV projection: Bt = [wq^T | wk^T | wv^T] as [2560][2048]
    k_transpose_w<<<dim3(32, 32), 256, 0, stream>>>(wq_l, wT, H_, NH_ * HD_);
    k_transpose_w<<<dim3(4, 32), 256, 0, stream>>>(wk_l, wT + (size_t)KOFF_ * H_, H_, NKV_ * HD_);
    k_transpose_w<<<dim3(4, 32), 256, 0, stream>>>(wv_l, wT + (size_t)VOFF_ * H_, H_, NKV_ * HD_);
    k_gemm<1, 1, 0, 0, 1><<<(QKVN_ / 128) * (S_ / 64), 256, 0, stream>>>(
        hnorm, wT, cbias + (size_t)l * QKVN_, nullptr, nullptr, qkv, S_, QKVN_, H_, H_, S_ / 64);
    // rope + cache build (also writes f32 present outputs)
    k_rope_q<<<(S_ * NH_ * 64) / 256, 256, 0, stream>>>(qkv, cos_t, sin_t, qrope);
    k_build_k<<<(NKV_ * T_ * 64) / 256, 256, 0, stream>>>(qkv, pk_in, cos_t, sin_t, kcache, pk_out);
    k_build_vt<<<dim3(T_ / 64, HD_ / 64, NKV_), 256, 0, stream>>>(qkv, pv_in, vtr, pv_out);
    // attention (balanced 1-D grid: complementary chunks per CU)
    k_attn<<<512, 128, 0, stream>>>(qrope, kcache, vtr, attno);
    // output projection + residual
    k_transpose_w<<<dim3(32, 32), 256, 0, stream>>>(wo_l, wT, NH_ * HD_, H_);
    k_gemm<0, 0, 1, 0, 1><<<(H_ / 128) * (S_ / 64), 256, 0, stream>>>(
        attno, wT, nullptr, hidden, nullptr, hidden, S_, H_, NH_ * HD_, NH_ * HD_, S_ / 64);
    // MLP: fused gate+up+SiLU (one GEMM, 32 MFMA/barrier-pair), then split-K down
    k_rmsnorm<1><<<S_, 256, 0, stream>>>(hidden, ln2 + (size_t)l * H_, hnorm);
    k_transpose_w<<<dim3(88, 32), 256, 0, stream>>>(wg_l, wT, H_, FF_);
    k_transpose_w<<<dim3(88, 32), 256, 0, stream>>>(wu_l, wTu, H_, FF_);
    k_gemm_gu<<<(FF_ / 128) * (S_ / 64), 256, 0, stream>>>(
        hnorm, wT, wTu, hgb, S_, FF_, H_, S_ / 64);
    k_transpose_w<<<dim3(32, 88), 256, 0, stream>>>(wd_l, wT, FF_, H_);
    // down: hidden already holds residual; 2 splits atomic-add their partials
    k_gemm<0, 0, 0, 0, 2><<<2 * (H_ / 128) * (S_ / 64), 256, 0, stream>>>(
        hgb, wT, nullptr, nullptr, nullptr, hidden, S_, H_, FF_, FF_ / 2, S_ / 64);
  }
  k_rmsnorm<0><<<S_, 256, 0, stream>>>(hidden, normw, out_h);
}

// Round 21
// 537.786 us; speedup vs baseline: 1.0391x; 1.0124x over previous
//
#include <hip/hip_runtime.h>

#define L_ 2
#define H_ 2048
#define NH_ 16
#define NKV_ 2
#define HD_ 128
#define S_ 1024
#define P_ 1024
#define T_ 2048
#define FF_ 5632
#define QKVN_ 2560   // NH*HD + 2*NKV*HD
#define KOFF_ 2048
#define VOFF_ 2304

#define EPS_ 1e-6f
#define SCALE_ 0.08838834764831845f   // 1/sqrt(128)
#define DEFER_THR_ 8.0f

typedef __bf16 bf16_t;
typedef unsigned int u32;
typedef __bf16 bx8 __attribute__((ext_vector_type(8)));
typedef __bf16 bx4 __attribute__((ext_vector_type(4)));
typedef float  fx4 __attribute__((ext_vector_type(4)));

__device__ __forceinline__ fx4 mfma16(bx8 a, bx8 b, fx4 c) {
  return __builtin_amdgcn_mfma_f32_16x16x32_bf16(a, b, c, 0, 0, 0);
}

// global->LDS direct, 16B per lane; lds dest = wave-uniform base + lane*16
#define GLL16(gsrc, ldst) __builtin_amdgcn_global_load_lds( \
    (__attribute__((address_space(1))) void*)(gsrc),        \
    (__attribute__((address_space(3))) void*)(ldst), 16, 0, 0)

// opaque LDS ops: compiler cannot attach vmem (global_load_lds) dependencies,
// so it cannot insert a hidden vmcnt(0) before them. Caller must lgkmcnt-fence.
__device__ __forceinline__ bx8 lds_read_b128(char* p) {
  u32 a = (u32)(uintptr_t)(__attribute__((address_space(3))) void*)p;
  bx8 d;
  asm volatile("ds_read_b128 %0, %1" : "=v"(d) : "v"(a));
  return d;
}
__device__ __forceinline__ void lds_write_b16(char* p, float v) {
  u32 a = (u32)(uintptr_t)(__attribute__((address_space(3))) void*)p;
  bf16_t b = (bf16_t)v;
  u32 d = (u32)__builtin_bit_cast(unsigned short, b);
  asm volatile("ds_write_b16 %0, %1" :: "v"(a), "v"(d));
}

#define LGKM(n) asm volatile("s_waitcnt lgkmcnt(" #n ")" ::: "memory"); __builtin_amdgcn_sched_barrier(0)

// non-temporal load for stream-once data: keeps L3 free for reused buffers
template<typename TT>
__device__ __forceinline__ TT nt_load(const TT* p) { return __builtin_nontemporal_load(p); }

// bijective XCD swizzle (m204): consecutive work-ids land on the same XCD
__device__ __forceinline__ int xcd_swizzle(int orig, int nwg) {
  int q = nwg >> 3, r = nwg & 7;
  int xcd = orig & 7, lid = orig >> 3;
  return (xcd < r ? xcd * (q + 1) : r * (q + 1) + (xcd - r) * q) + lid;
}

// ---------------- RoPE tables ----------------
__global__ void k_rope_tables(const int* __restrict__ pos, float* __restrict__ ct, float* __restrict__ st) {
  int i = blockIdx.x * 256 + threadIdx.x;
  if (i >= S_ * 64) return;
  int s = i >> 6, d = i & 63;
  float p = (float)pos[s];
  float inv = expf(-(float)(2 * d) * (13.815510557964274f / 128.0f));  // theta=1e6
  float f = p * inv;
  ct[i] = cosf(f);
  st[i] = sinf(f);
}

__global__ void k_copy4(const float* __restrict__ in, float* __restrict__ out, int n4) {
  int i = blockIdx.x * 256 + threadIdx.x;
  if (i < n4) ((fx4*)out)[i] = nt_load(&((const fx4*)in)[i]);
}

// concat bias: [L][2560] = bq | bk | bv
__global__ void k_cbias(const float* __restrict__ bq, const float* __restrict__ bk,
                        const float* __restrict__ bv, float* __restrict__ cb) {
  int i = blockIdx.x * 256 + threadIdx.x;
  if (i >= L_ * QKVN_) return;
  int l = i / QKVN_, j = i % QKVN_;
  float v;
  if (j < KOFF_)      v = bq[l * KOFF_ + j];
  else if (j < VOFF_) v = bk[l * (NKV_ * HD_) + j - KOFF_];
  else                v = bv[l * (NKV_ * HD_) + j - VOFF_];
  cb[i] = v;
}

// ---------------- RMSNorm (one block per row) ----------------
template<int OUTBF>
__global__ __launch_bounds__(256) void k_rmsnorm(const float* __restrict__ x, const float* __restrict__ w,
                                                 void* __restrict__ y) {
  int row = blockIdx.x, tid = threadIdx.x;
  const fx4* xr = (const fx4*)(x + (size_t)row * H_);
  fx4 v0 = xr[tid], v1 = xr[tid + 256];
  float ss = v0[0]*v0[0] + v0[1]*v0[1] + v0[2]*v0[2] + v0[3]*v0[3]
           + v1[0]*v1[0] + v1[1]*v1[1] + v1[2]*v1[2] + v1[3]*v1[3];
  #pragma unroll
  for (int off = 32; off > 0; off >>= 1) ss += __shfl_xor(ss, off);
  __shared__ float red[4];
  if ((tid & 63) == 0) red[tid >> 6] = ss;
  __syncthreads();
  float tot = red[0] + red[1] + red[2] + red[3];
  float rs = rsqrtf(tot * (1.0f / H_) + EPS_);
  const fx4* wr_ = (const fx4*)w;
  fx4 w0 = wr_[tid], w1 = wr_[tid + 256];
  if (OUTBF) {
    bf16_t* yb = (bf16_t*)y + (size_t)row * H_;
    bx4 o0, o1;
    #pragma unroll
    for (int i = 0; i < 4; i++) { o0[i] = (bf16_t)(v0[i] * rs * w0[i]); o1[i] = (bf16_t)(v1[i] * rs * w1[i]); }
    *(bx4*)&yb[tid * 4] = o0;
    *(bx4*)&yb[(tid + 256) * 4] = o1;
  } else {
    float* yf = (float*)y + (size_t)row * H_;
    fx4 o0, o1;
    #pragma unroll
    for (int i = 0; i < 4; i++) { o0[i] = v0[i] * rs * w0[i]; o1[i] = v1[i] * rs * w1[i]; }
    *(fx4*)&yf[tid * 4] = o0;
    *(fx4*)&yf[(tid + 256) * 4] = o1;
  }
}

// ---------------- weight transpose+convert: out[C][R] = bf16(in[R][C]^T) ----------------
// Input f32 reads are NON-TEMPORAL (stream-once): keeps the bf16 outputs
// L3-resident for the GEMMs that read them next.
__global__ __launch_bounds__(256) void k_transpose_w(const float* __restrict__ in, bf16_t* __restrict__ out,
                                                     int R, int C) {
  __shared__ __attribute__((aligned(16))) float Tt[64 * 68];
  int tid = threadIdx.x;
  int c0 = blockIdx.x * 64, r0 = blockIdx.y * 64;
  #pragma unroll
  for (int j = 0; j < 4; j++) {
    int c = j * 256 + tid;
    int row = c >> 4, col = (c & 15) * 4;
    *(fx4*)&Tt[row * 68 + col] = nt_load((const fx4*)&in[(size_t)(r0 + row) * C + c0 + col]);
  }
  __syncthreads();
  #pragma unroll
  for (int j = 0; j < 2; j++) {
    int c = j * 256 + tid;
    int n = c >> 3, ko = (c & 7) * 8;
    bx8 o;
    #pragma unroll
    for (int i = 0; i < 8; i++) o[i] = (bf16_t)Tt[(ko + i) * 68 + n];
    *(bx8*)&out[(size_t)(c0 + n) * R + r0 + ko] = o;
  }
}

// ---------------- GEMM 64x128: C[M,N] = A[M,K](bf16) * Bt[N,K]^T ----------------
// 2-buffer depth-1 pipeline (48KB LDS), counted vmcnt(6), raw s_barrier,
// opaque asm ds_read_b128, split-lgkm(6/0) + setprio.
// SPLIT>1: each split does kLen of K and atomicAdds f32 partials into out.
template<int OUTBF, int HASB, int HASR, int HASG, int SPLIT>
__global__ __launch_bounds__(256) void k_gemm(const bf16_t* __restrict__ A, const bf16_t* __restrict__ Bt,
                                              const float* __restrict__ bias, const float* __restrict__ res,
                                              const bf16_t* __restrict__ gmul,
                                              void* __restrict__ out, int M, int N, int lda, int kLen, int gy) {
  __shared__ __attribute__((aligned(16))) bf16_t sA[2][64 * 64];
  __shared__ __attribute__((aligned(16))) bf16_t sB[2][128 * 64];
  int tid = threadIdx.x;
  int w = tid >> 6, lane = tid & 63, g = lane >> 4, r = lane & 15;
  int wr = w >> 1, wc = w & 1;
  int swzid = xcd_swizzle((int)blockIdx.x, (int)gridDim.x);
  int per = (int)gridDim.x / SPLIT;
  int sp = swzid / per;
  int rem = swzid - sp * per;
  int m0 = (rem % gy) * 64;
  int n0 = (rem / gy) * 128;
  A  += (size_t)sp * kLen;
  Bt += (size_t)sp * kLen;
  fx4 acc[2][4] = {};
  int swz = (r & 7) << 4;
  int col0 = (g * 16) ^ swz;
  int col1 = (64 + g * 16) ^ swz;
  int wbase = (tid & ~63) * 16;
  int nk = kLen >> 6;

  auto STAGE = [&](int buf, int k0) {
    #pragma unroll
    for (int j = 0; j < 2; j++) {
      int d = (j * 256 + tid) * 16;
      int row = d >> 7;
      int inrow = (d & 127) ^ ((row & 7) << 4);
      GLL16((const char*)(A + (size_t)(m0 + row) * lda + k0) + inrow,
            (char*)&sA[buf][0] + j * 4096 + wbase);
    }
    #pragma unroll
    for (int j = 0; j < 4; j++) {
      int d = (j * 256 + tid) * 16;
      int row = d >> 7;
      int inrow = (d & 127) ^ ((row & 7) << 4);
      GLL16((const char*)(Bt + (size_t)(n0 + row) * lda + k0) + inrow,
            (char*)&sB[buf][0] + j * 4096 + wbase);
    }
  };

  STAGE(0, 0);                                     // 6 outstanding
  int cur = 0;
  for (int t = 0; t < nk; t++) {
    if (t + 1 < nk) {
      STAGE(cur ^ 1, (t + 1) << 6);                // 12 outstanding
      asm volatile("s_waitcnt vmcnt(6)" ::: "memory");  // cur's loads landed
    } else {
      asm volatile("s_waitcnt vmcnt(0)" ::: "memory");
    }
    __builtin_amdgcn_s_barrier();                  // all waves' cur-stage visible
    __builtin_amdgcn_sched_barrier(0);
    char* pa = (char*)&sA[cur][0] + (wr * 32 + r) * 128;
    char* pb = (char*)&sB[cur][0] + (wc * 64 + r) * 128;
    bx8 fa[2][2], fb[4][2];
    fa[0][0] = lds_read_b128(pa + col0);
    fa[1][0] = lds_read_b128(pa + 2048 + col0);
    #pragma unroll
    for (int n = 0; n < 4; n++) fb[n][0] = lds_read_b128(pb + n * 2048 + col0);
    fa[0][1] = lds_read_b128(pa + col1);
    fa[1][1] = lds_read_b128(pa + 2048 + col1);
    #pragma unroll
    for (int n = 0; n < 4; n++) fb[n][1] = lds_read_b128(pb + n * 2048 + col1);
    LGKM(6);                                       // col0 set complete
    __builtin_amdgcn_s_setprio(1);
    #pragma unroll
    for (int n = 0; n < 4; n++) {
      acc[0][n] = mfma16(fa[0][0], fb[n][0], acc[0][n]);
      acc[1][n] = mfma16(fa[1][0], fb[n][0], acc[1][n]);
    }
    __builtin_amdgcn_s_setprio(0);
    LGKM(0);                                       // col1 set complete
    __builtin_amdgcn_s_setprio(1);
    #pragma unroll
    for (int n = 0; n < 4; n++) {
      acc[0][n] = mfma16(fa[0][1], fb[n][1], acc[0][n]);
      acc[1][n] = mfma16(fa[1][1], fb[n][1], acc[1][n]);
    }
    __builtin_amdgcn_s_setprio(0);
    if (t + 1 < nk) {
      __builtin_amdgcn_s_barrier();                // reads done before buf reuse
      __builtin_amdgcn_sched_barrier(0);
    }
    cur ^= 1;
  }
  #pragma unroll
  for (int m = 0; m < 2; m++)
    #pragma unroll
    for (int n = 0; n < 4; n++) {
      int col = n0 + wc * 64 + n * 16 + r;
      #pragma unroll
      for (int rr = 0; rr < 4; rr++) {
        int row = m0 + wr * 32 + m * 16 + 4 * g + rr;
        float v = acc[m][n][rr];
        if (SPLIT > 1) {
          atomicAdd(&((float*)out)[(size_t)row * N + col], v);
        } else {
          if (HASB) v += bias[col];
          if (HASR) v += res[(size_t)row * N + col];
          if (HASG) {
            float x = (float)gmul[(size_t)row * N + col];
            v = (x / (1.0f + __expf(-x))) * v;
          }
          if (OUTBF) ((bf16_t*)out)[(size_t)row * N + col] = (bf16_t)v;
          else       ((float*)out)[(size_t)row * N + col] = v;
        }
      }
    }
}

// ---------------- fused gate+up GEMM + SiLU: out = silu(A*Bg^T) * (A*Bu^T) ----------------
// 64x128 tile, 2-buffer depth-1 pipeline (80KB LDS), counted vmcnt(10),
// opaque reads, split-lgkm(10/0) + setprio; 32 MFMA per barrier-pair.
__global__ __launch_bounds__(256) void k_gemm_gu(const bf16_t* __restrict__ A, const bf16_t* __restrict__ Bg,
                                                 const bf16_t* __restrict__ Bu, bf16_t* __restrict__ out,
                                                 int M, int N, int lda, int gy) {
  __shared__ __attribute__((aligned(16))) bf16_t sA[2][64 * 64];
  __shared__ __attribute__((aligned(16))) bf16_t sBg[2][128 * 64];
  __shared__ __attribute__((aligned(16))) bf16_t sBu[2][128 * 64];
  int tid = threadIdx.x;
  int w = tid >> 6, lane = tid & 63, g = lane >> 4, r = lane & 15;
  int wr = w >> 1, wc = w & 1;
  int swzid = xcd_swizzle((int)blockIdx.x, (int)gridDim.x);
  int m0 = (swzid % gy) * 64;
  int n0 = (swzid / gy) * 128;
  fx4 accg[2][4] = {}, accu[2][4] = {};
  int swz = (r & 7) << 4;
  int col0 = (g * 16) ^ swz;
  int col1 = (64 + g * 16) ^ swz;
  int wbase = (tid & ~63) * 16;
  int nk = lda >> 6;   // K == lda here

  auto STAGE = [&](int buf, int k0) {
    #pragma unroll
    for (int j = 0; j < 2; j++) {
      int d = (j * 256 + tid) * 16;
      int row = d >> 7;
      int inrow = (d & 127) ^ ((row & 7) << 4);
      GLL16((const char*)(A + (size_t)(m0 + row) * lda + k0) + inrow,
            (char*)&sA[buf][0] + j * 4096 + wbase);
    }
    #pragma unroll
    for (int j = 0; j < 4; j++) {
      int d = (j * 256 + tid) * 16;
      int row = d >> 7;
      int inrow = (d & 127) ^ ((row & 7) << 4);
      GLL16((const char*)(Bg + (size_t)(n0 + row) * lda + k0) + inrow,
            (char*)&sBg[buf][0] + j * 4096 + wbase);
    }
    #pragma unroll
    for (int j = 0; j < 4; j++) {
      int d = (j * 256 + tid) * 16;
      int row = d >> 7;
      int inrow = (d & 127) ^ ((row & 7) << 4);
      GLL16((const char*)(Bu + (size_t)(n0 + row) * lda + k0) + inrow,
            (char*)&sBu[buf][0] + j * 4096 + wbase);
    }
  };

  STAGE(0, 0);                                     // 10 outstanding
  int cur = 0;
  for (int t = 0; t < nk; t++) {
    if (t + 1 < nk) {
      STAGE(cur ^ 1, (t + 1) << 6);                // 20 outstanding
      asm volatile("s_waitcnt vmcnt(10)" ::: "memory");  // cur's 10 landed
    } else {
      asm volatile("s_waitcnt vmcnt(0)" ::: "memory");
    }
    __builtin_amdgcn_s_barrier();
    __builtin_amdgcn_sched_barrier(0);
    char* pa = (char*)&sA[cur][0] + (wr * 32 + r) * 128;
    char* pg = (char*)&sBg[cur][0] + (wc * 64 + r) * 128;
    char* pu = (char*)&sBu[cur][0] + (wc * 64 + r) * 128;
    bx8 fa[2][2], fg[4][2], fu[4][2];
    // col0 set: 10 reads, then col1 set: 10 reads (DS completes in order)
    fa[0][0] = lds_read_b128(pa + col0);
    fa[1][0] = lds_read_b128(pa + 2048 + col0);
    #pragma unroll
    for (int n = 0; n < 4; n++) fg[n][0] = lds_read_b128(pg + n * 2048 + col0);
    #pragma unroll
    for (int n = 0; n < 4; n++) fu[n][0] = lds_read_b128(pu + n * 2048 + col0);
    fa[0][1] = lds_read_b128(pa + col1);
    fa[1][1] = lds_read_b128(pa + 2048 + col1);
    #pragma unroll
    for (int n = 0; n < 4; n++) fg[n][1] = lds_read_b128(pg + n * 2048 + col1);
    #pragma unroll
    for (int n = 0; n < 4; n++) fu[n][1] = lds_read_b128(pu + n * 2048 + col1);
    LGKM(10);                                      // col0 set complete
    __builtin_amdgcn_s_setprio(1);
    #pragma unroll
    for (int n = 0; n < 4; n++) {
      accg[0][n] = mfma16(fa[0][0], fg[n][0], accg[0][n]);
      accg[1][n] = mfma16(fa[1][0], fg[n][0], accg[1][n]);
      accu[0][n] = mfma16(fa[0][0], fu[n][0], accu[0][n]);
      accu[1][n] = mfma16(fa[1][0], fu[n][0], accu[1][n]);
    }
    __builtin_amdgcn_s_setprio(0);
    LGKM(0);                                       // col1 set complete
    __builtin_amdgcn_s_setprio(1);
    #pragma unroll
    for (int n = 0; n < 4; n++) {
      accg[0][n] = mfma16(fa[0][1], fg[n][1], accg[0][n]);
      accg[1][n] = mfma16(fa[1][1], fg[n][1], accg[1][n]);
      accu[0][n] = mfma16(fa[0][1], fu[n][1], accu[0][n]);
      accu[1][n] = mfma16(fa[1][1], fu[n][1], accu[1][n]);
    }
    __builtin_amdgcn_s_setprio(0);
    if (t + 1 < nk) {
      __builtin_amdgcn_s_barrier();
      __builtin_amdgcn_sched_barrier(0);
    }
    cur ^= 1;
  }
  #pragma unroll
  for (int m = 0; m < 2; m++)
    #pragma unroll
    for (int n = 0; n < 4; n++) {
      int col = n0 + wc * 64 + n * 16 + r;
      #pragma unroll
      for (int rr = 0; rr < 4; rr++) {
        int row = m0 + wr * 32 + m * 16 + 4 * g + rr;
        float x = accg[m][n][rr];
        float u = accu[m][n][rr];
        float s = x / (1.0f + __expf(-x));
        out[(size_t)row * N + col] = (bf16_t)(s * u);
      }
    }
}

// ---------------- RoPE on Q: qkv[S][2560] bf16 -> [NH][S][HD] bf16 ----------------
__global__ void k_rope_q(const bf16_t* __restrict__ qkv, const float* __restrict__ ct,
                         const float* __restrict__ st, bf16_t* __restrict__ qout) {
  int i = blockIdx.x * 256 + threadIdx.x;
  if (i >= S_ * NH_ * 64) return;
  int d = i & 63, h = (i >> 6) & 15, s = i >> 10;
  size_t ib = (size_t)s * QKVN_ + h * HD_;
  float x1 = (float)qkv[ib + d];
  float x2 = (float)qkv[ib + d + 64];
  float c = ct[s * 64 + d], sn = st[s * 64 + d];
  size_t ob = ((size_t)h * S_ + s) * HD_;
  qout[ob + d]      = (bf16_t)(x1 * c - x2 * sn);
  qout[ob + d + 64] = (bf16_t)(x2 * c + x1 * sn);
}

// ---------------- K: rope new keys + concat past -> bf16 [NKV][T][HD] + f32 present ----------------
__global__ void k_build_k(const bf16_t* __restrict__ qkv, const float* __restrict__ pastk,
                          const float* __restrict__ ct, const float* __restrict__ st,
                          bf16_t* __restrict__ kc, float* __restrict__ pk_out) {
  int i = blockIdx.x * 256 + threadIdx.x;
  if (i >= NKV_ * T_ * 64) return;
  int d = i & 63, t = (i >> 6) & (T_ - 1), kv = i >> 17;
  size_t cb = ((size_t)kv * T_ + t) * HD_;
  if (t < P_) {
    size_t pb = ((size_t)kv * P_ + t) * HD_;
    float a = nt_load(&pastk[pb + d]), b = nt_load(&pastk[pb + d + 64]);
    kc[cb + d] = (bf16_t)a; kc[cb + d + 64] = (bf16_t)b;
    pk_out[cb + d] = a;     pk_out[cb + d + 64] = b;
  } else {
    int s = t - P_;
    size_t ib = (size_t)s * QKVN_ + KOFF_ + kv * HD_;
    float x1 = (float)qkv[ib + d];
    float x2 = (float)qkv[ib + d + 64];
    float c = ct[s * 64 + d], sn = st[s * 64 + d];
    float k1 = x1 * c - x2 * sn, k2 = x2 * c + x1 * sn;
    kc[cb + d] = (bf16_t)k1; kc[cb + d + 64] = (bf16_t)k2;
    pk_out[cb + d] = k1;     pk_out[cb + d + 64] = k2;
  }
}

// ---------------- V: concat past+new -> VT bf16 [NKV][HD][T] + f32 present ----------------
__global__ __launch_bounds__(256) void k_build_vt(const bf16_t* __restrict__ qkv, const float* __restrict__ pastv,
                                                  bf16_t* __restrict__ vt, float* __restrict__ pv_out) {
  int t0 = blockIdx.x * 64, d0 = blockIdx.y * 64, kv = blockIdx.z;
  __shared__ __attribute__((aligned(16))) float Tt[64 * 68];
  int tid = threadIdx.x;
  if (t0 < P_) {
    #pragma unroll
    for (int j = 0; j < 4; j++) {
      int c = j * 256 + tid;
      int row = c >> 4, col = (c & 15) * 4;
      int t = t0 + row;
      fx4 v = nt_load((const fx4*)&pastv[((size_t)kv * P_ + t) * HD_ + d0 + col]);
      *(fx4*)&Tt[row * 68 + col] = v;
      *(fx4*)&pv_out[((size_t)kv * T_ + t) * HD_ + d0 + col] = v;
    }
  } else {
    #pragma unroll
    for (int j = 0; j < 4; j++) {
      int c = j * 256 + tid;
      int row = c >> 4, col = (c & 15) * 4;
      int t = t0 + row;
      bx4 b = *(const bx4*)&qkv[(size_t)(t - P_) * QKVN_ + VOFF_ + kv * HD_ + d0 + col];
      fx4 v;
      #pragma unroll
      for (int q = 0; q < 4; q++) v[q] = (float)b[q];
      *(fx4*)&Tt[row * 68 + col] = v;
      *(fx4*)&pv_out[((size_t)kv * T_ + t) * HD_ + d0 + col] = v;
    }
  }
  __syncthreads();
  #pragma unroll
  for (int j = 0; j < 2; j++) {
    int c = j * 256 + tid;
    int n = c >> 3, ko = (c & 7) * 8;
    bx8 o;
    #pragma unroll
    for (int i = 0; i < 8; i++) o[i] = (bf16_t)Tt[(ko + i) * 68 + n];
    *(bx8*)&vt[((size_t)kv * HD_ + d0 + n) * T_ + t0 + ko] = o;
  }
}

// ---------------- flash attention (stable 62us): balanced chunk mapping ----------------
__global__ __launch_bounds__(128) void k_attn(const bf16_t* __restrict__ Q, const bf16_t* __restrict__ Kc,
                                              const bf16_t* __restrict__ VT, bf16_t* __restrict__ O) {
  __shared__ __attribute__((aligned(16))) bf16_t Klds[2][64 * 128];
  __shared__ __attribute__((aligned(16))) bf16_t Vlds[2][128 * 64];
  __shared__ __attribute__((aligned(16))) bf16_t Plds[2][16][72];
  int tid = threadIdx.x;               // 0..127
  int w = tid >> 6, lane = tid & 63, g = lane >> 4, r = lane & 15;
  int b = blockIdx.x;                  // 0..511
  int half = b >> 8;                   // = kv
  int idx = b & 255;
  int cx = idx & 31;
  int chunk = half ? (31 - cx) : cx;   // complementary chunks land on same CU
  int h = (half << 3) | (idx >> 5);    // heads 0-7 (kv0) / 8-15 (kv1)
  int kv = half;
  int m0 = chunk * 32;
  int qr0 = m0 + w * 16;
  const bf16_t* qb = Q + ((size_t)h * S_ + qr0 + r) * HD_ + g * 8;
  bx8 qf[4];
  #pragma unroll
  for (int kc = 0; kc < 4; kc++) qf[kc] = *(const bx8*)(qb + kc * 32);
  fx4 of[8] = {};
  float mrun[4], lrun[4];
  #pragma unroll
  for (int i = 0; i < 4; i++) { mrun[i] = -1e30f; lrun[i] = 0.0f; }
  int lim = P_ + qr0 + 4 * g;
  int ntile = (P_ + m0 + 32 + 63) >> 6;
  const char* kg = (const char*)(Kc + (size_t)kv * T_ * HD_);
  const char* vg = (const char*)(VT + (size_t)kv * HD_ * T_);
  int wbase = (tid & ~63) * 16;        // w*1024

  auto STAGE = [&](int buf, int t0) {
    #pragma unroll
    for (int j = 0; j < 8; j++) {      // K: 64 rows x 256B = 16KB, 2KB/round
      int D = j * 2048 + tid * 16;
      int row = D >> 8, inrow = D & 255;
      const char* src = kg + (size_t)(t0 + row) * 256 + (inrow ^ ((row & 7) << 4));
      GLL16(src, (char*)&Klds[buf][0] + j * 2048 + wbase);
    }
    #pragma unroll
    for (int j = 0; j < 8; j++) {      // V^T: 128 rows x 128B = 16KB
      int D = j * 2048 + tid * 16;
      int row = D >> 7, inrow = D & 127;
      const char* src = vg + (size_t)row * 4096 + (size_t)t0 * 2 + (inrow ^ ((row & 7) << 4));
      GLL16(src, (char*)&Vlds[buf][0] + j * 2048 + wbase);
    }
  };

  STAGE(0, 0);
  asm volatile("s_waitcnt vmcnt(0)" ::: "memory");
  __builtin_amdgcn_s_barrier();
  __builtin_amdgcn_sched_barrier(0);
  int cur = 0;
  for (int t = 0; t < ntile; t++) {
    int t0 = t * 64;
    if (t + 1 < ntile) {
      STAGE(cur ^ 1, t0 + 64);                             // issue next tile (16 vm ops)
      asm volatile("s_waitcnt vmcnt(16)" ::: "memory");    // cur's stage landed
    } else {
      asm volatile("s_waitcnt vmcnt(0)" ::: "memory");
    }
    __builtin_amdgcn_s_barrier();                          // all waves' cur-stage visible
    __builtin_amdgcn_sched_barrier(0);
    // ---- QK^T: 16 opaque ds_reads, counted lgkm, interleaved MFMAs ----
    char* kb = (char*)&Klds[cur][0];
    char* vb = (char*)&Vlds[cur][0];
    bx8 kf[4][4];
    #pragma unroll
    for (int nt = 0; nt < 4; nt++) {
      int row = nt * 16 + r;
      char* kr = kb + row * 256;
      int sz = (row & 7) << 4;
      #pragma unroll
      for (int kc = 0; kc < 4; kc++)
        kf[nt][kc] = lds_read_b128(kr + (((kc * 32 + g * 8) * 2) ^ sz));
    }
    fx4 sc[4] = {};
    LGKM(12);
    #pragma unroll
    for (int kc = 0; kc < 4; kc++) sc[0] = mfma16(qf[kc], kf[0][kc], sc[0]);
    LGKM(8);
    #pragma unroll
    for (int kc = 0; kc < 4; kc++) sc[1] = mfma16(qf[kc], kf[1][kc], sc[1]);
    LGKM(4);
    #pragma unroll
    for (int kc = 0; kc < 4; kc++) sc[2] = mfma16(qf[kc], kf[2][kc], sc[2]);
    LGKM(0);
    #pragma unroll
    for (int kc = 0; kc < 4; kc++) sc[3] = mfma16(qf[kc], kf[3][kc], sc[3]);
    // ---- issue all 16 V reads; latency hides under softmax VALU ----
    bx8 vf0[8], vf1[8];
    #pragma unroll
    for (int dt = 0; dt < 8; dt++) {
      int row = dt * 16 + r;
      vf0[dt] = lds_read_b128(vb + row * 128 + (((g * 8) * 2) ^ ((row & 7) << 4)));
    }
    #pragma unroll
    for (int dt = 0; dt < 8; dt++) {
      int row = dt * 16 + r;
      vf1[dt] = lds_read_b128(vb + row * 128 + (((32 + g * 8) * 2) ^ ((row & 7) << 4)));
    }
    // ---- softmax (defer-max) ----
    float lm[4] = {-1e30f, -1e30f, -1e30f, -1e30f};
    #pragma unroll
    for (int nt = 0; nt < 4; nt++)
      #pragma unroll
      for (int rr = 0; rr < 4; rr++) {
        int key = t0 + nt * 16 + r;
        float sv = sc[nt][rr] * SCALE_;
        sv = (key > lim + rr) ? -1e30f : sv;
        sc[nt][rr] = sv;
        lm[rr] = fmaxf(lm[rr], sv);
      }
    int ok = (lm[0] <= mrun[0] + DEFER_THR_) & (lm[1] <= mrun[1] + DEFER_THR_) &
             (lm[2] <= mrun[2] + DEFER_THR_) & (lm[3] <= mrun[3] + DEFER_THR_);
    if (!__all(ok)) {
      float av[4];
      #pragma unroll
      for (int off = 1; off < 16; off <<= 1)
        #pragma unroll
        for (int rr = 0; rr < 4; rr++) lm[rr] = fmaxf(lm[rr], __shfl_xor(lm[rr], off));
      #pragma unroll
      for (int rr = 0; rr < 4; rr++) {
        float mn = fmaxf(mrun[rr], lm[rr]);
        av[rr] = __expf(mrun[rr] - mn);
        mrun[rr] = mn;
        lrun[rr] *= av[rr];
      }
      #pragma unroll
      for (int f = 0; f < 8; f++)
        #pragma unroll
        for (int rr = 0; rr < 4; rr++) of[f][rr] *= av[rr];
    }
    // P writes: cols 0-31 then pa0 read; cols 32-63 then pa1
    #pragma unroll
    for (int nt = 0; nt < 2; nt++)
      #pragma unroll
      for (int rr = 0; rr < 4; rr++) {
        float pr = __expf(sc[nt][rr] - mrun[rr]);
        lrun[rr] += pr;
        lds_write_b16((char*)&Plds[w][4 * g + rr][nt * 16 + r], pr);
      }
    bx8 pa0 = lds_read_b128((char*)&Plds[w][r][g * 8]);
    #pragma unroll
    for (int nt = 2; nt < 4; nt++)
      #pragma unroll
      for (int rr = 0; rr < 4; rr++) {
        float pr = __expf(sc[nt][rr] - mrun[rr]);
        lrun[rr] += pr;
        lds_write_b16((char*)&Plds[w][4 * g + rr][nt * 16 + r], pr);
      }
    bx8 pa1 = lds_read_b128((char*)&Plds[w][r][32 + g * 8]);
    LGKM(9);    // pa0 complete (8 writes + pa1 remain)
    #pragma unroll
    for (int dt = 0; dt < 8; dt++) of[dt] = mfma16(pa0, vf0[dt], of[dt]);
    LGKM(0);    // pa1 complete
    #pragma unroll
    for (int dt = 0; dt < 8; dt++) of[dt] = mfma16(pa1, vf1[dt], of[dt]);
    __builtin_amdgcn_s_barrier();                          // all waves done reading cur
    cur ^= 1;
  }
  #pragma unroll
  for (int off = 1; off < 16; off <<= 1)
    #pragma unroll
    for (int rr = 0; rr < 4; rr++) lrun[rr] += __shfl_xor(lrun[rr], off);
  float li[4];
  #pragma unroll
  for (int rr = 0; rr < 4; rr++) li[rr] = 1.0f / lrun[rr];
  #pragma unroll
  for (int dt = 0; dt < 8; dt++)
    #pragma unroll
    for (int rr = 0; rr < 4; rr++)
      O[(size_t)(qr0 + 4 * g + rr) * H_ + h * HD_ + dt * 16 + r] = (bf16_t)(of[dt][rr] * li[rr]);
}

// ---------------- host-side launch ----------------
extern "C" void kernel_launch(void* const* d_in, const int* in_sizes, int n_in,
                              void* d_out, int out_size, void* d_ws, size_t ws_size,
                              hipStream_t stream) {
  const float* embeds = (const float*)d_in[0];
  const int*   pos    = (const int*)d_in[1];
  const float* past_k = (const float*)d_in[2];
  const float* past_v = (const float*)d_in[3];
  const float* ln1    = (const float*)d_in[4];
  const float* wq     = (const float*)d_in[5];
  const float* bq     = (const float*)d_in[6];
  const float* wk     = (const float*)d_in[7];
  const float* bk     = (const float*)d_in[8];
  const float* wv     = (const float*)d_in[9];
  const float* bv     = (const float*)d_in[10];
  const float* wo     = (const float*)d_in[11];
  const float* ln2    = (const float*)d_in[12];
  const float* wg     = (const float*)d_in[13];
  const float* wu     = (const float*)d_in[14];
  const float* wd     = (const float*)d_in[15];
  const float* normw  = (const float*)d_in[16];

  char* wsp = (char*)d_ws;
  auto take = [&](size_t n) { char* p = wsp; wsp += (n + 255) & ~(size_t)255; return (void*)p; };
  float*  cos_t  = (float*)take((size_t)S_ * 64 * 4);
  float*  sin_t  = (float*)take((size_t)S_ * 64 * 4);
  float*  cbias  = (float*)take((size_t)L_ * QKVN_ * 4);
  float*  hidden = (float*)take((size_t)S_ * H_ * 4);
  bf16_t* hnorm  = (bf16_t*)take((size_t)S_ * H_ * 2);
  bf16_t* qkv    = (bf16_t*)take((size_t)S_ * QKVN_ * 2);
  bf16_t* qrope  = (bf16_t*)take((size_t)NH_ * S_ * HD_ * 2);
  bf16_t* kcache = (bf16_t*)take((size_t)NKV_ * T_ * HD_ * 2);
  bf16_t* vtr    = (bf16_t*)take((size_t)NKV_ * HD_ * T_ * 2);
  bf16_t* attno  = (bf16_t*)take((size_t)S_ * H_ * 2);
  bf16_t* hgb    = (bf16_t*)take((size_t)S_ * FF_ * 2);
  bf16_t* wT     = (bf16_t*)take((size_t)FF_ * H_ * 2);   // 23 MB (gate / qkv / wo / down)
  bf16_t* wTu    = (bf16_t*)take((size_t)FF_ * H_ * 2);   // 23 MB (up)

  float* out_h = (float*)d_out;

  k_rope_tables<<<256, 256, 0, stream>>>(pos, cos_t, sin_t);
  k_cbias<<<(L_ * QKVN_ + 255) / 256, 256, 0, stream>>>(bq, bk, bv, cbias);
  k_copy4<<<(S_ * H_ / 4 + 255) / 256, 256, 0, stream>>>(embeds, hidden, S_ * H_ / 4);

  for (int l = 0; l < L_; l++) {
    const float* wq_l = wq + (size_t)l * H_ * (NH_ * HD_);
    const float* wk_l = wk + (size_t)l * H_ * (NKV_ * HD_);
    const float* wv_l = wv + (size_t)l * H_ * (NKV_ * HD_);
    const float* wo_l = wo + (size_t)l * (NH_ * HD_) * H_;
    const float* wg_l = wg + (size_t)l * H_ * FF_;
    const float* wu_l = wu + (size_t)l * H_ * FF_;
    const float* wd_l = wd + (size_t)l * FF_ * H_;
    const float* pk_in = past_k + (size_t)l * NKV_ * P_ * HD_;
    const float* pv_in = past_v + (size_t)l * NKV_ * P_ * HD_;
    float* pk_out = out_h + (size_t)S_ * H_ + (size_t)l * 2 * NKV_ * T_ * HD_;
    float* pv_out = pk_out + (size_t)NKV_ * T_ * HD_;

    // attn input norm
    k_rmsnorm<1><<<S_, 256, 0, stream>>>(hidden, ln1 + (size_t)l * H_, hnorm);
    // fused QKV projection: Bt = [wq^T | wk^T | wv^T] as [2560][2048]
    k_transpose_w<<<dim3(32, 32), 256, 0, stream>>>(wq_l, wT, H_, NH_ * HD_);
    k_transpose_w<<<dim3(4, 32), 256, 0, stream>>>(wk_l, wT + (size_t)KOFF_ * H_, H_, NKV_ * HD_);
    k_transpose_w<<<dim3(4, 32), 256, 0, stream>>>(wv_l, wT + (size_t)VOFF_ * H_, H_, NKV_ * HD_);
    k_gemm<1, 1, 0, 0, 1><<<(QKVN_ / 128) * (S_ / 64), 256, 0, stream>>>(
        hnorm, wT, cbias + (size_t)l * QKVN_, nullptr, nullptr, qkv, S_, QKVN_, H_, H_, S_ / 64);
    // rope + cache build (also writes f32 present outputs)
    k_rope_q<<<(S_ * NH_ * 64) / 256, 256, 0, stream>>>(qkv, cos_t, sin_t, qrope);
    k_build_k<<<(NKV_ * T_ * 64) / 256, 256, 0, stream>>>(qkv, pk_in, cos_t, sin_t, kcache, pk_out);
    k_build_vt<<<dim3(T_ / 64, HD_ / 64, NKV_), 256, 0, stream>>>(qkv, pv_in, vtr, pv_out);
    // attention (balanced 1-D grid: complementary chunks per CU)
    k_attn<<<512, 128, 0, stream>>>(qrope, kcache, vtr, attno);
    // output projection + residual
    k_transpose_w<<<dim3(32, 32), 256, 0, stream>>>(wo_l, wT, NH_ * HD_, H_);
    k_gemm<0, 0, 1, 0, 1><<<(H_ / 128) * (S_ / 64), 256, 0, stream>>>(
        attno, wT, nullptr, hidden, nullptr, hidden, S_, H_, NH_ * HD_, NH_ * HD_, S_ / 64);
    // MLP: fused gate+up+SiLU (one GEMM, 32 MFMA/barrier-pair), then split-K down
    k_rmsnorm<1><<<S_, 256, 0, stream>>>(hidden, ln2 + (size_t)l * H_, hnorm);
    k_transpose_w<<<dim3(88, 32), 256, 0, stream>>>(wg_l, wT, H_, FF_);
    k_transpose_w<<<dim3(88, 32), 256, 0, stream>>>(wu_l, wTu, H_, FF_);
    k_gemm_gu<<<(FF_ / 128) * (S_ / 64), 256, 0, stream>>>(
        hnorm, wT, wTu, hgb, S_, FF_, H_, S_ / 64);
    k_transpose_w<<<dim3(32, 88), 256, 0, stream>>>(wd_l, wT, FF_, H_);
    // down: hidden already holds residual; 2 splits atomic-add their partials
    k_gemm<0, 0, 0, 0, 2><<<2 * (H_ / 128) * (S_ / 64), 256, 0, stream>>>(
        hgb, wT, nullptr, nullptr, nullptr, hidden, S_, H_, FF_, FF_ / 2, S_ / 64);
  }
  k_rmsnorm<0><<<S_, 256, 0, stream>>>(hidden, normw, out_h);
}